// Round 4
// baseline (883.762 us; speedup 1.0000x reference)
//
#include <hip/hip_runtime.h>
#include <hip/hip_bf16.h>
#include <hip/hip_fp16.h>
#include <math.h>

#define NN 262144
#define EE 2097152
#define NPER 32768

typedef float4 f4;

// ---------------- in-degree count via dst (for CSR + dis), int4-vectorized
__global__ __launch_bounds__(256) void k_degree(const int* __restrict__ ei, int* __restrict__ cnt) {
  int i = blockIdx.x * 256 + threadIdx.x;          // 524288 threads x 4 edges
  int4 d4 = ((const int4*)(ei + EE))[i];
  atomicAdd(&cnt[d4.x], 1);
  atomicAdd(&cnt[d4.y], 1);
  atomicAdd(&cnt[d4.z], 1);
  atomicAdd(&cnt[d4.w], 1);
}

// ---------------- exclusive scan of cnt over N (3 kernels)
__global__ __launch_bounds__(256) void k_scanA(const int* __restrict__ cnt, int* __restrict__ bsum) {
  __shared__ int sm[256];
  int t = threadIdx.x;
  int base = blockIdx.x * 1024 + t * 4;
  int s = cnt[base] + cnt[base + 1] + cnt[base + 2] + cnt[base + 3];
  sm[t] = s;
  __syncthreads();
  for (int off = 128; off > 0; off >>= 1) {
    if (t < off) sm[t] += sm[t + off];
    __syncthreads();
  }
  if (t == 0) bsum[blockIdx.x] = sm[0];
}

__global__ __launch_bounds__(256) void k_scanB(const int* __restrict__ bsum, int* __restrict__ bscan) {
  __shared__ int sm[256];
  int t = threadIdx.x;
  int orig = bsum[t];
  sm[t] = orig;
  __syncthreads();
  for (int off = 1; off < 256; off <<= 1) {
    int v = (t >= off) ? sm[t - off] : 0;
    __syncthreads();
    sm[t] += v;
    __syncthreads();
  }
  bscan[t] = sm[t] - orig;  // exclusive
}

__global__ __launch_bounds__(256) void k_scanC(const int* __restrict__ cnt, const int* __restrict__ bscan,
                                               int* __restrict__ offs, int* __restrict__ cur,
                                               float* __restrict__ dis) {
  __shared__ int sm[256];
  int t = threadIdx.x;
  int base = blockIdx.x * 1024 + t * 4;
  int c0 = cnt[base], c1 = cnt[base + 1], c2 = cnt[base + 2], c3 = cnt[base + 3];
  int s = c0 + c1 + c2 + c3;
  sm[t] = s;
  __syncthreads();
  for (int off = 1; off < 256; off <<= 1) {
    int v = (t >= off) ? sm[t - off] : 0;
    __syncthreads();
    sm[t] += v;
    __syncthreads();
  }
  int ex = sm[t] - s + bscan[blockIdx.x];
  int o0 = ex, o1 = ex + c0, o2 = o1 + c1, o3 = o2 + c2;
  offs[base] = o0; offs[base + 1] = o1; offs[base + 2] = o2; offs[base + 3] = o3;
  cur[base] = o0;  cur[base + 1] = o1;  cur[base + 2] = o2;  cur[base + 3] = o3;
  dis[base]     = rsqrtf((float)(c0 + 1));   // +1 = self loop
  dis[base + 1] = rsqrtf((float)(c1 + 1));
  dis[base + 2] = rsqrtf((float)(c2 + 1));
  dis[base + 3] = rsqrtf((float)(c3 + 1));
}

// ---------------- CSR fill + layer-1 class-weight accumulation (8-class trick) + out-degree
__global__ __launch_bounds__(256) void k_fill(const int* __restrict__ ei, const int* __restrict__ x,
                                              const float* __restrict__ dis, float* __restrict__ w8,
                                              int* __restrict__ cur, int* __restrict__ adj,
                                              int* __restrict__ dega) {
  int stride = gridDim.x * blockDim.x;
  for (int e = blockIdx.x * blockDim.x + threadIdx.x; e < EE; e += stride) {
    int s = ei[e];
    int d = ei[EE + e];
    float nrm = dis[s] * dis[d];
    int c = x[s];
    atomicAdd(&w8[(size_t)d * 8 + c], nrm);
    atomicAdd(&dega[s], 1);
    int pos = atomicAdd(&cur[d], 1);
    adj[pos] = s;
  }
}

// ---------------- M1 = emb_w @ W2  (8x64)
__global__ void k_m1(const float* __restrict__ emb, const float* __restrict__ W2, float* __restrict__ M1) {
  int t = threadIdx.x;  // 512 threads
  int c = t >> 6, j = t & 63;
  float acc = 0.f;
  for (int k = 0; k < 64; ++k) acc += emb[c * 64 + k] * W2[k * 64 + j];
  M1[c * 64 + j] = acc;
}

// ---------------- out1h = fp16( dis[n] * relu(w8(+self)@M1 + b2) )   (16 threads/node)
__global__ __launch_bounds__(256) void k_out1(const float* __restrict__ w8, const float* __restrict__ dis,
                                              const int* __restrict__ x, const float* __restrict__ M1,
                                              const float* __restrict__ b2, __half2* __restrict__ out1h) {
  int tid = blockIdx.x * 256 + threadIdx.x;
  int node = tid >> 4, part = tid & 15;
  const f4* wr = (const f4*)&w8[(size_t)node * 8];
  f4 w0 = wr[0], w1 = wr[1];
  float wv[8] = {w0.x, w0.y, w0.z, w0.w, w1.x, w1.y, w1.z, w1.w};
  float dn = dis[node];
  float d2 = dn * dn;
  int xc = x[node];
#pragma unroll
  for (int c = 0; c < 8; ++c) wv[c] += (c == xc) ? d2 : 0.f;  // layer-1 self loop, static idx
  int j0 = part * 4;
  float o0 = b2[j0], o1 = b2[j0 + 1], o2 = b2[j0 + 2], o3 = b2[j0 + 3];
#pragma unroll
  for (int c = 0; c < 8; ++c) {
    f4 m = *(const f4*)&M1[c * 64 + j0];
    o0 += wv[c] * m.x; o1 += wv[c] * m.y; o2 += wv[c] * m.z; o3 += wv[c] * m.w;
  }
  // relu, pre-scale by dis[node], pack fp16
  __half2 h01 = __floats2half2_rn(fmaxf(o0, 0.f) * dn, fmaxf(o1, 0.f) * dn);
  __half2 h23 = __floats2half2_rn(fmaxf(o2, 0.f) * dn, fmaxf(o3, 0.f) * dn);
  size_t p = (size_t)node * 32 + part * 2;
  out1h[p] = h01;
  out1h[p + 1] = h23;
}

// ---------------- layer 2: CSR gather of prescaled fp16 out1, then @W3+b3,relu + @W1+b1 + softmax
__global__ __launch_bounds__(256) void k_layer2(const int* __restrict__ adj, const int* __restrict__ offs,
                                                const int* __restrict__ cnt, const float* __restrict__ dis,
                                                const __half2* __restrict__ out1h,
                                                const float* __restrict__ W3, const float* __restrict__ b3,
                                                const float* __restrict__ W1, const float* __restrict__ b1,
                                                float* __restrict__ dout) {
  __shared__ float aggl[16 * 68];
  __shared__ float o2l[16 * 68];
  int tid = threadIdx.x;
  int bid = blockIdx.x;
  int swz = (bid & 7) * 2048 + (bid >> 3);      // XCD-local graphs: 2048 blocks == 1 graph == 1 XCD
  int lane = tid & 63;
  int sub = lane >> 4, part = lane & 15;
  int ndl = ((tid >> 6) << 2) + sub;            // 0..15 node-local
  int node = swz * 16 + ndl;
  int j0 = part * 4;

  // phase 1: agg = dn * sum(out1h[self] + out1h[neighbors])   (all prescaled by dis[src])
  float dn = dis[node];
  int off = offs[node];
  int c = cnt[node];
  const __half2* sp = out1h + (size_t)node * 32 + part * 2;
  float2 f01 = __half22float2(sp[0]), f23 = __half22float2(sp[1]);
  float ax = f01.x, ay = f01.y, az = f23.x, aw = f23.y;
  for (int it = 0; it < c; ++it) {
    int s = adj[off + it];
    const __half2* hp = out1h + (size_t)s * 32 + part * 2;
    __half2 h01 = hp[0], h23 = hp[1];
    float2 g01 = __half22float2(h01), g23 = __half22float2(h23);
    ax += g01.x; ay += g01.y; az += g23.x; aw += g23.y;
  }
  f4 st; st.x = dn * ax; st.y = dn * ay; st.z = dn * az; st.w = dn * aw;
  *(f4*)&aggl[ndl * 68 + j0] = st;
  __syncthreads();

  // phase 3a: o2 = relu(agg @ W3 + b3). thread owns column j for 4 nodes (W3 reg reuse x4)
  {
    int w = tid >> 6;       // node group 0..3
    int j = tid & 63;
    float bb = b3[j];
    float o0 = bb, o1 = bb, o2 = bb, o3 = bb;
    for (int k = 0; k < 64; ++k) {
      float wk = W3[k * 64 + j];
      o0 += aggl[(w * 4 + 0) * 68 + k] * wk;
      o1 += aggl[(w * 4 + 1) * 68 + k] * wk;
      o2 += aggl[(w * 4 + 2) * 68 + k] * wk;
      o3 += aggl[(w * 4 + 3) * 68 + k] * wk;
    }
    o2l[(w * 4 + 0) * 68 + j] = fmaxf(o0, 0.f);
    o2l[(w * 4 + 1) * 68 + j] = fmaxf(o1, 0.f);
    o2l[(w * 4 + 2) * 68 + j] = fmaxf(o2, 0.f);
    o2l[(w * 4 + 3) * 68 + j] = fmaxf(o3, 0.f);
  }
  __syncthreads();

  // phase 3b: s = o2 @ W1 + b1, softmax over 16 lanes
  int nd2 = tid >> 4, t16 = tid & 15;
  float sv = b1[t16];
  const float* o2p = &o2l[nd2 * 68];
  for (int j = 0; j < 64; ++j) sv += o2p[j] * W1[j * 16 + t16];
  float mx = sv;
#pragma unroll
  for (int m = 1; m < 16; m <<= 1) mx = fmaxf(mx, __shfl_xor(mx, m));
  float ex = expf(sv - mx);
  float sm = ex;
#pragma unroll
  for (int m = 1; m < 16; m <<= 1) sm += __shfl_xor(sm, m);
  dout[8 + (size_t)swz * 256 + tid] = ex / sm;  // == s_b[node][t16], coalesced per block
}

// ---------------- mincut numerator via CSR: num[g] += s_b[d] . sum_{s in adj[d]} s_b[s]
__global__ __launch_bounds__(256) void k_num(const int* __restrict__ adj, const int* __restrict__ offs,
                                             const int* __restrict__ cnt, const float* __restrict__ sb,
                                             float* __restrict__ num) {
  __shared__ float red[16];
  int tid = threadIdx.x;
  int bid = blockIdx.x;
  int swz = (bid & 7) * 2048 + (bid >> 3);
  int grp = tid >> 4, t16 = tid & 15;
  int node = swz * 16 + grp;
  int off = offs[node];
  int c = cnt[node];
  float sv = 0.f;
  for (int it = 0; it < c; ++it) {
    int s = adj[off + it];
    sv += sb[(size_t)s * 16 + t16];
  }
  float local = sb[(size_t)node * 16 + t16] * sv;
#pragma unroll
  for (int m = 1; m < 16; m <<= 1) local += __shfl_xor(local, m);
  if (t16 == 0) red[grp] = local;
  __syncthreads();
  if (tid == 0) {
    float acc = 0.f;
#pragma unroll
    for (int i = 0; i < 16; ++i) acc += red[i];
    atomicAdd(&num[swz >> 11], acc);
  }
}

// ---------------- den + xp + SS per graph (block = 256 contiguous nodes)
__global__ __launch_bounds__(256) void k_ssden(const float* __restrict__ sb, const int* __restrict__ dega,
                                               float* __restrict__ den, float* __restrict__ xp,
                                               float* __restrict__ SSb) {
  __shared__ float sl[256 * 17];
  __shared__ float red[256];
  __shared__ float xpl[16];
  int t = threadIdx.x;
  int b = blockIdx.x;
  int g = b >> 7;          // 128 blocks per graph
  int t1 = t >> 4, t2 = t & 15;
  if (t < 16) xpl[t] = 0.f;
  int node = b * 256 + t;
  const f4* pr = (const f4*)&sb[(size_t)node * 16];
  f4 r0 = pr[0], r1 = pr[1], r2 = pr[2], r3 = pr[3];
  float q = r0.x * r0.x + r0.y * r0.y + r0.z * r0.z + r0.w * r0.w
          + r1.x * r1.x + r1.y * r1.y + r1.z * r1.z + r1.w * r1.w
          + r2.x * r2.x + r2.y * r2.y + r2.z * r2.z + r2.w * r2.w
          + r3.x * r3.x + r3.y * r3.y + r3.z * r3.z + r3.w * r3.w;
  float denloc = q * (float)dega[node];
  float* row = &sl[t * 17];
  row[0] = r0.x; row[1] = r0.y; row[2] = r0.z; row[3] = r0.w;
  row[4] = r1.x; row[5] = r1.y; row[6] = r1.z; row[7] = r1.w;
  row[8] = r2.x; row[9] = r2.y; row[10] = r2.z; row[11] = r2.w;
  row[12] = r3.x; row[13] = r3.y; row[14] = r3.z; row[15] = r3.w;
  __syncthreads();
  float ss = 0.f;
  for (int n = 0; n < 256; ++n) ss += sl[n * 17 + t1] * sl[n * 17 + t2];
  atomicAdd(&SSb[g * 256 + t], ss);
  // xp partial sums (per-column totals of this block's 256 rows)
  atomicAdd(&xpl[t2], (t1 == 0) ? 0.f : 0.f);  // no-op to keep xpl in scope; real sums below
  red[t] = denloc;
  __syncthreads();
  for (int off = 128; off > 0; off >>= 1) {
    if (t < off) red[t] += red[t + off];
    __syncthreads();
  }
  if (t == 0) atomicAdd(&den[g], red[0]);
  // xp: reuse sl (already synced): column t2 sum over the 16 rows owned by t1 group
  {
    float colsum = 0.f;
#pragma unroll
    for (int r = 0; r < 16; ++r) colsum += sl[(t1 * 16 + r) * 17 + t2];
    atomicAdd(&xpl[t2], colsum);
    __syncthreads();
    if (t < 16) atomicAdd(&xp[g * 16 + t], xpl[t]);
  }
}

// ---------------- scalars: mc1, o1, pred
__global__ __launch_bounds__(256) void k_final(const float* __restrict__ accum, const float* __restrict__ ncells,
                                               const float* __restrict__ Wp, const float* __restrict__ bp,
                                               float* __restrict__ dout) {
  __shared__ float red[256];
  __shared__ float bc;
  int t = threadIdx.x;
  const float* num = accum;
  const float* den = accum + 8;
  const float* xp  = accum + 16;
  const float* SSb = accum + 144;
  float o1s = 0.f;
  for (int g = 0; g < 8; ++g) {
    float v = SSb[g * 256 + t];
    red[t] = v * v;
    __syncthreads();
    for (int off = 128; off > 0; off >>= 1) {
      if (t < off) red[t] += red[t + off];
      __syncthreads();
    }
    if (t == 0) bc = sqrtf(red[0]);
    __syncthreads();
    float nrm = bc;
    float diag = ((t >> 4) == (t & 15)) ? 0.25f : 0.f;  // I/sqrt(16)
    float dv = v / nrm - diag;
    red[t] = dv * dv;
    __syncthreads();
    for (int off = 128; off > 0; off >>= 1) {
      if (t < off) red[t] += red[t + off];
      __syncthreads();
    }
    if (t == 0) o1s += sqrtf(red[0]);
    __syncthreads();
  }
  if (t == 0) {
    dout[8 + (size_t)NN * 16 + 1] = o1s / 8.f;
    float m = 0.f;
    for (int g = 0; g < 8; ++g) m += -num[g] / den[g];
    dout[8 + (size_t)NN * 16] = m / 8.f;
  }
  if (t < 8) {
    float p = bp[0];
    for (int k = 0; k < 16; ++k) p += (xp[t * 16 + k] / ncells[t]) * Wp[k];
    dout[t] = p;
  }
}

extern "C" void kernel_launch(void* const* d_in, const int* in_sizes, int n_in,
                              void* d_out, int out_size, void* d_ws, size_t ws_size,
                              hipStream_t stream) {
  const int* x            = (const int*)d_in[0];
  const int* ei           = (const int*)d_in[1];   // int32 (JAX x64 disabled)
  const float* ncells     = (const float*)d_in[3];
  const float* emb        = (const float*)d_in[4];
  const float* W2         = (const float*)d_in[5];
  const float* b2         = (const float*)d_in[6];
  const float* W3         = (const float*)d_in[7];
  const float* b3         = (const float*)d_in[8];
  const float* W1         = (const float*)d_in[9];
  const float* b1         = (const float*)d_in[10];
  const float* Wp         = (const float*)d_in[11];
  const float* bp         = (const float*)d_in[12];
  float* dout = (float*)d_out;

  // workspace layout (~54 MB)
  char* w = (char*)d_ws;
  int* cnt     = (int*)w;                              // N
  int* dega    = cnt + NN;                             // N
  float* w8    = (float*)(dega + NN);                  // 8N
  float* accum = w8 + (size_t)8 * NN;                  // 2192 floats: num8, den8, xp128, SS2048
  float* num   = accum;
  float* den   = accum + 8;
  float* xp    = accum + 16;
  float* SSb   = accum + 144;
  float* dis   = accum + 2192;                         // N
  int* offs    = (int*)(dis + NN);                     // N
  int* cur     = offs + NN;                            // N
  int* adj     = cur + NN;                             // E
  int* bsum    = adj + EE;                             // 256
  int* bscan   = bsum + 256;                           // 256
  float* M1    = (float*)(bscan + 256);                // 512
  __half2* out1h = (__half2*)(M1 + 512);               // N*32 half2 = 32 MB

  size_t zbytes = (size_t)(10 * NN) * 4 + 2192 * 4;    // cnt, dega, w8, accum
  hipMemsetAsync(d_ws, 0, zbytes, stream);

  k_degree<<<2048, 256, 0, stream>>>(ei, cnt);
  k_scanA <<<256, 256, 0, stream>>>(cnt, bsum);
  k_scanB <<<1, 256, 0, stream>>>(bsum, bscan);
  k_scanC <<<256, 256, 0, stream>>>(cnt, bscan, offs, cur, dis);
  k_fill  <<<2048, 256, 0, stream>>>(ei, x, dis, w8, cur, adj, dega);
  k_m1    <<<1, 512, 0, stream>>>(emb, W2, M1);
  k_out1  <<<16384, 256, 0, stream>>>(w8, dis, x, M1, b2, out1h);
  k_layer2<<<16384, 256, 0, stream>>>(adj, offs, cnt, dis, out1h, W3, b3, W1, b1, dout);
  k_num   <<<16384, 256, 0, stream>>>(adj, offs, cnt, dout + 8, num);
  k_ssden <<<1024, 256, 0, stream>>>(dout + 8, dega, den, xp, SSb);
  k_final <<<1, 256, 0, stream>>>(accum, ncells, Wp, bp, dout);
}

// Round 5
// 831.633 us; speedup vs baseline: 1.0627x; 1.0627x over previous
//
#include <hip/hip_runtime.h>
#include <hip/hip_bf16.h>
#include <hip/hip_fp16.h>
#include <math.h>

#define NN 262144
#define EE 2097152
#define NPER 32768
#define EPG 262144   // edges per graph

typedef float4 f4;

// ---------------- pass 1: per-block (512 nodes of one graph) count in-degree from dst scan.
// Zero global atomics: LDS counters, coalesced writeout. Blocks of graph g pinned to XCD g (bid&7).
__global__ __launch_bounds__(512) void k_count(const int* __restrict__ ei, const int* __restrict__ x,
                                               int* __restrict__ cnt, float* __restrict__ dis,
                                               float2* __restrict__ dx) {
  __shared__ int cntl[512];
  int t = threadIdx.x;
  int bid = blockIdx.x;
  int g = bid & 7;            // graph == XCD (round-robin dispatch)
  int blk = bid >> 3;         // 0..63 within graph
  int lo = g * NPER + blk * 512;
  cntl[t] = 0;
  __syncthreads();
  const int4* dst4 = (const int4*)(ei + EE + (size_t)g * EPG);
#pragma unroll 4
  for (int j = 0; j < 128; ++j) {
    int4 d4 = dst4[j * 512 + t];
    if ((unsigned)(d4.x - lo) < 512u) atomicAdd(&cntl[d4.x - lo], 1);
    if ((unsigned)(d4.y - lo) < 512u) atomicAdd(&cntl[d4.y - lo], 1);
    if ((unsigned)(d4.z - lo) < 512u) atomicAdd(&cntl[d4.z - lo], 1);
    if ((unsigned)(d4.w - lo) < 512u) atomicAdd(&cntl[d4.w - lo], 1);
  }
  __syncthreads();
  int c = cntl[t];
  int n = lo + t;
  cnt[n] = c;
  float dn = rsqrtf((float)(c + 1));   // +1 self loop
  dis[n] = dn;
  dx[n] = make_float2(dn, __int_as_float(x[n]));
}

// ---------------- exclusive scan of cnt over N (3 kernels)
__global__ __launch_bounds__(256) void k_scanA(const int* __restrict__ cnt, int* __restrict__ bsum) {
  __shared__ int sm[256];
  int t = threadIdx.x;
  int base = blockIdx.x * 1024 + t * 4;
  int s = cnt[base] + cnt[base + 1] + cnt[base + 2] + cnt[base + 3];
  sm[t] = s;
  __syncthreads();
  for (int off = 128; off > 0; off >>= 1) {
    if (t < off) sm[t] += sm[t + off];
    __syncthreads();
  }
  if (t == 0) bsum[blockIdx.x] = sm[0];
}

__global__ __launch_bounds__(256) void k_scanB(const int* __restrict__ bsum, int* __restrict__ bscan) {
  __shared__ int sm[256];
  int t = threadIdx.x;
  int orig = bsum[t];
  sm[t] = orig;
  __syncthreads();
  for (int off = 1; off < 256; off <<= 1) {
    int v = (t >= off) ? sm[t - off] : 0;
    __syncthreads();
    sm[t] += v;
    __syncthreads();
  }
  bscan[t] = sm[t] - orig;  // exclusive
}

__global__ __launch_bounds__(256) void k_scanC(const int* __restrict__ cnt, const int* __restrict__ bscan,
                                               int* __restrict__ offs) {
  __shared__ int sm[256];
  int t = threadIdx.x;
  int base = blockIdx.x * 1024 + t * 4;
  int c0 = cnt[base], c1 = cnt[base + 1], c2 = cnt[base + 2], c3 = cnt[base + 3];
  int s = c0 + c1 + c2 + c3;
  sm[t] = s;
  __syncthreads();
  for (int off = 1; off < 256; off <<= 1) {
    int v = (t >= off) ? sm[t - off] : 0;
    __syncthreads();
    sm[t] += v;
    __syncthreads();
  }
  int ex = sm[t] - s + bscan[blockIdx.x];
  offs[base] = ex; offs[base + 1] = ex + c0; offs[base + 2] = ex + c0 + c1; offs[base + 3] = ex + c0 + c1 + c2;
}

// ---------------- pass 2: CSR fill. Block owns 512 dsts; LDS cursor; adj writes land in the
// block's exclusive ~16KB window -> L2 write-combined (no global atomics).
__global__ __launch_bounds__(512) void k_fill2(const int* __restrict__ ei, const int* __restrict__ offs,
                                               int* __restrict__ adj) {
  __shared__ int curl[512];
  int t = threadIdx.x;
  int bid = blockIdx.x;
  int g = bid & 7;
  int blk = bid >> 3;
  int lo = g * NPER + blk * 512;
  curl[t] = offs[lo + t];
  __syncthreads();
  const int4* src4 = (const int4*)(ei + (size_t)g * EPG);
  const int4* dst4 = (const int4*)(ei + EE + (size_t)g * EPG);
  for (int j = 0; j < 128; ++j) {
    int4 s4 = src4[j * 512 + t];
    int4 d4 = dst4[j * 512 + t];
    if ((unsigned)(d4.x - lo) < 512u) adj[atomicAdd(&curl[d4.x - lo], 1)] = s4.x;
    if ((unsigned)(d4.y - lo) < 512u) adj[atomicAdd(&curl[d4.y - lo], 1)] = s4.y;
    if ((unsigned)(d4.z - lo) < 512u) adj[atomicAdd(&curl[d4.z - lo], 1)] = s4.z;
    if ((unsigned)(d4.w - lo) < 512u) adj[atomicAdd(&curl[d4.w - lo], 1)] = s4.w;
  }
}

// ---------------- M1 = emb_w @ W2  (8x64)
__global__ void k_m1(const float* __restrict__ emb, const float* __restrict__ W2, float* __restrict__ M1) {
  int t = threadIdx.x;  // 512 threads
  int c = t >> 6, j = t & 63;
  float acc = 0.f;
  for (int k = 0; k < 64; ++k) acc += emb[c * 64 + k] * W2[k * 64 + j];
  M1[c * 64 + j] = acc;
}

// ---------------- out1h = fp16( dis[n] * relu(W8row@M1 + b2) ); W8row gathered from CSR.
// 16 threads/node; predicated 8-class accumulate + shfl reduce.
__global__ __launch_bounds__(256) void k_out1(const int* __restrict__ adj, const int* __restrict__ offs,
                                              const int* __restrict__ cnt, const float2* __restrict__ dx,
                                              const float* __restrict__ M1, const float* __restrict__ b2,
                                              __half2* __restrict__ out1h) {
  int tid = threadIdx.x;
  int bid = blockIdx.x;
  int swz = (bid & 7) * 2048 + (bid >> 3);    // XCD-local graph
  int node = swz * 16 + (tid >> 4);
  int t16 = tid & 15;
  float2 dxn = dx[node];
  float dn = dxn.x;
  int xc = __float_as_int(dxn.y);
  int off = offs[node], c = cnt[node];
  float wv[8] = {0.f, 0.f, 0.f, 0.f, 0.f, 0.f, 0.f, 0.f};
  for (int it = t16; it < c; it += 16) {
    int s = adj[off + it];
    float2 v = dx[s];
    int cls = __float_as_int(v.y);
#pragma unroll
    for (int k = 0; k < 8; ++k) wv[k] += (cls == k) ? v.x : 0.f;
  }
#pragma unroll
  for (int k = 0; k < 8; ++k) {
#pragma unroll
    for (int m = 1; m < 16; m <<= 1) wv[k] += __shfl_xor(wv[k], m);
    wv[k] = (wv[k] + ((k == xc) ? dn : 0.f)) * dn;   // + self (dis), scale by dis[d]
  }
  int j0 = t16 * 4;
  float o0 = b2[j0], o1 = b2[j0 + 1], o2 = b2[j0 + 2], o3 = b2[j0 + 3];
#pragma unroll
  for (int k = 0; k < 8; ++k) {
    f4 m = *(const f4*)&M1[k * 64 + j0];
    o0 += wv[k] * m.x; o1 += wv[k] * m.y; o2 += wv[k] * m.z; o3 += wv[k] * m.w;
  }
  __half2 h01 = __floats2half2_rn(fmaxf(o0, 0.f) * dn, fmaxf(o1, 0.f) * dn);
  __half2 h23 = __floats2half2_rn(fmaxf(o2, 0.f) * dn, fmaxf(o3, 0.f) * dn);
  size_t p = (size_t)node * 32 + t16 * 2;
  out1h[p] = h01;
  out1h[p + 1] = h23;
}

// ---------------- layer 2: CSR gather of prescaled fp16 out1 (4-way chunked), @W3+b3,relu,
// @W1+b1, softmax -> d_out
__global__ __launch_bounds__(256) void k_layer2(const int* __restrict__ adj, const int* __restrict__ offs,
                                                const int* __restrict__ cnt, const float* __restrict__ dis,
                                                const __half2* __restrict__ out1h,
                                                const float* __restrict__ W3, const float* __restrict__ b3,
                                                const float* __restrict__ W1, const float* __restrict__ b1,
                                                float* __restrict__ dout) {
  __shared__ float aggl[16 * 68];
  __shared__ float o2l[16 * 68];
  int tid = threadIdx.x;
  int bid = blockIdx.x;
  int swz = (bid & 7) * 2048 + (bid >> 3);
  int lane = tid & 63;
  int sub = lane >> 4, part = lane & 15;
  int ndl = ((tid >> 6) << 2) + sub;
  int node = swz * 16 + ndl;
  int j0 = part * 4;

  float dn = dis[node];
  int off = offs[node];
  int c = cnt[node];
  const __half2* sp = out1h + (size_t)node * 32 + part * 2;
  float2 f01 = __half22float2(sp[0]), f23 = __half22float2(sp[1]);
  float ax = f01.x, ay = f01.y, az = f23.x, aw = f23.y;   // self (prescaled)
  int it = 0;
  for (; it + 4 <= c; it += 4) {
    int s0 = adj[off + it], s1 = adj[off + it + 1], s2 = adj[off + it + 2], s3 = adj[off + it + 3];
    const __half2* p0 = out1h + (size_t)s0 * 32 + part * 2;
    const __half2* p1 = out1h + (size_t)s1 * 32 + part * 2;
    const __half2* p2 = out1h + (size_t)s2 * 32 + part * 2;
    const __half2* p3 = out1h + (size_t)s3 * 32 + part * 2;
    __half2 a0 = p0[0], c0 = p0[1], a1 = p1[0], c1 = p1[1];
    __half2 a2 = p2[0], c2 = p2[1], a3 = p3[0], c3 = p3[1];
    float2 u;
    u = __half22float2(a0); ax += u.x; ay += u.y;  u = __half22float2(c0); az += u.x; aw += u.y;
    u = __half22float2(a1); ax += u.x; ay += u.y;  u = __half22float2(c1); az += u.x; aw += u.y;
    u = __half22float2(a2); ax += u.x; ay += u.y;  u = __half22float2(c2); az += u.x; aw += u.y;
    u = __half22float2(a3); ax += u.x; ay += u.y;  u = __half22float2(c3); az += u.x; aw += u.y;
  }
  for (; it < c; ++it) {
    int s = adj[off + it];
    const __half2* hp = out1h + (size_t)s * 32 + part * 2;
    float2 g01 = __half22float2(hp[0]), g23 = __half22float2(hp[1]);
    ax += g01.x; ay += g01.y; az += g23.x; aw += g23.y;
  }
  f4 st; st.x = dn * ax; st.y = dn * ay; st.z = dn * az; st.w = dn * aw;
  *(f4*)&aggl[ndl * 68 + j0] = st;
  __syncthreads();

  // o2 = relu(agg @ W3 + b3)
  {
    int w = tid >> 6;
    int j = tid & 63;
    float bb = b3[j];
    float o0 = bb, o1 = bb, o2 = bb, o3 = bb;
    for (int k = 0; k < 64; ++k) {
      float wk = W3[k * 64 + j];
      o0 += aggl[(w * 4 + 0) * 68 + k] * wk;
      o1 += aggl[(w * 4 + 1) * 68 + k] * wk;
      o2 += aggl[(w * 4 + 2) * 68 + k] * wk;
      o3 += aggl[(w * 4 + 3) * 68 + k] * wk;
    }
    o2l[(w * 4 + 0) * 68 + j] = fmaxf(o0, 0.f);
    o2l[(w * 4 + 1) * 68 + j] = fmaxf(o1, 0.f);
    o2l[(w * 4 + 2) * 68 + j] = fmaxf(o2, 0.f);
    o2l[(w * 4 + 3) * 68 + j] = fmaxf(o3, 0.f);
  }
  __syncthreads();

  // s = o2 @ W1 + b1, softmax over 16 lanes
  int nd2 = tid >> 4, t16 = tid & 15;
  float sv = b1[t16];
  const float* o2p = &o2l[nd2 * 68];
  for (int j = 0; j < 64; ++j) sv += o2p[j] * W1[j * 16 + t16];
  float mx = sv;
#pragma unroll
  for (int m = 1; m < 16; m <<= 1) mx = fmaxf(mx, __shfl_xor(mx, m));
  float ex = expf(sv - mx);
  float sm = ex;
#pragma unroll
  for (int m = 1; m < 16; m <<= 1) sm += __shfl_xor(sm, m);
  dout[8 + (size_t)swz * 256 + tid] = ex / sm;
}

// ---------------- mincut num + den via CSR:
// num[g] += s_b[d] . sum_{s in adj[d]} s_b[s];  den[g] += sum_{s in adj[d]} ||s_b[s]||^2
__global__ __launch_bounds__(256) void k_num(const int* __restrict__ adj, const int* __restrict__ offs,
                                             const int* __restrict__ cnt, const float* __restrict__ sb,
                                             float* __restrict__ num, float* __restrict__ den) {
  __shared__ float redn[16];
  __shared__ float redd[16];
  int tid = threadIdx.x;
  int bid = blockIdx.x;
  int swz = (bid & 7) * 2048 + (bid >> 3);
  int grp = tid >> 4, t16 = tid & 15;
  int node = swz * 16 + grp;
  int off = offs[node];
  int c = cnt[node];
  float sv = 0.f, sq = 0.f;
  int it = 0;
  for (; it + 4 <= c; it += 4) {
    int s0 = adj[off + it], s1 = adj[off + it + 1], s2 = adj[off + it + 2], s3 = adj[off + it + 3];
    float v0 = sb[(size_t)s0 * 16 + t16];
    float v1 = sb[(size_t)s1 * 16 + t16];
    float v2 = sb[(size_t)s2 * 16 + t16];
    float v3 = sb[(size_t)s3 * 16 + t16];
    sv += v0 + v1 + v2 + v3;
    sq += v0 * v0 + v1 * v1 + v2 * v2 + v3 * v3;
  }
  for (; it < c; ++it) {
    float v = sb[(size_t)adj[off + it] * 16 + t16];
    sv += v;
    sq += v * v;
  }
  float dot = sb[(size_t)node * 16 + t16] * sv;
#pragma unroll
  for (int m = 1; m < 16; m <<= 1) {
    dot += __shfl_xor(dot, m);
    sq  += __shfl_xor(sq, m);
  }
  if (t16 == 0) { redn[grp] = dot; redd[grp] = sq; }
  __syncthreads();
  if (tid == 0) {
    float a = 0.f, b = 0.f;
#pragma unroll
    for (int i = 0; i < 16; ++i) { a += redn[i]; b += redd[i]; }
    int g = swz >> 11;
    atomicAdd(&num[g], a);
    atomicAdd(&den[g], b);
  }
}

// ---------------- xp + SS per graph (block = 256 contiguous nodes)
__global__ __launch_bounds__(256) void k_ssden(const float* __restrict__ sb,
                                               float* __restrict__ xp, float* __restrict__ SSb) {
  __shared__ float sl[256 * 17];
  __shared__ float xpl[16];
  int t = threadIdx.x;
  int b = blockIdx.x;
  int g = b >> 7;          // 128 blocks per graph
  int t1 = t >> 4, t2 = t & 15;
  if (t < 16) xpl[t] = 0.f;
  int node = b * 256 + t;
  const f4* pr = (const f4*)&sb[(size_t)node * 16];
  f4 r0 = pr[0], r1 = pr[1], r2 = pr[2], r3 = pr[3];
  float* row = &sl[t * 17];
  row[0] = r0.x; row[1] = r0.y; row[2] = r0.z; row[3] = r0.w;
  row[4] = r1.x; row[5] = r1.y; row[6] = r1.z; row[7] = r1.w;
  row[8] = r2.x; row[9] = r2.y; row[10] = r2.z; row[11] = r2.w;
  row[12] = r3.x; row[13] = r3.y; row[14] = r3.z; row[15] = r3.w;
  __syncthreads();
  float ss = 0.f;
  for (int n = 0; n < 256; ++n) ss += sl[n * 17 + t1] * sl[n * 17 + t2];
  atomicAdd(&SSb[g * 256 + t], ss);
  float colsum = 0.f;
#pragma unroll
  for (int r = 0; r < 16; ++r) colsum += sl[(t1 * 16 + r) * 17 + t2];
  atomicAdd(&xpl[t2], colsum);
  __syncthreads();
  if (t < 16) atomicAdd(&xp[g * 16 + t], xpl[t]);
}

// ---------------- scalars: mc1, o1, pred
__global__ __launch_bounds__(256) void k_final(const float* __restrict__ accum, const float* __restrict__ ncells,
                                               const float* __restrict__ Wp, const float* __restrict__ bp,
                                               float* __restrict__ dout) {
  __shared__ float red[256];
  __shared__ float bc;
  int t = threadIdx.x;
  const float* num = accum;
  const float* den = accum + 8;
  const float* xp  = accum + 16;
  const float* SSb = accum + 144;
  float o1s = 0.f;
  for (int g = 0; g < 8; ++g) {
    float v = SSb[g * 256 + t];
    red[t] = v * v;
    __syncthreads();
    for (int off = 128; off > 0; off >>= 1) {
      if (t < off) red[t] += red[t + off];
      __syncthreads();
    }
    if (t == 0) bc = sqrtf(red[0]);
    __syncthreads();
    float nrm = bc;
    float diag = ((t >> 4) == (t & 15)) ? 0.25f : 0.f;  // I/sqrt(16)
    float dv = v / nrm - diag;
    red[t] = dv * dv;
    __syncthreads();
    for (int off = 128; off > 0; off >>= 1) {
      if (t < off) red[t] += red[t + off];
      __syncthreads();
    }
    if (t == 0) o1s += sqrtf(red[0]);
    __syncthreads();
  }
  if (t == 0) {
    dout[8 + (size_t)NN * 16 + 1] = o1s / 8.f;
    float m = 0.f;
    for (int g = 0; g < 8; ++g) m += -num[g] / den[g];
    dout[8 + (size_t)NN * 16] = m / 8.f;
  }
  if (t < 8) {
    float p = bp[0];
    for (int k = 0; k < 16; ++k) p += (xp[t * 16 + k] / ncells[t]) * Wp[k];
    dout[t] = p;
  }
}

extern "C" void kernel_launch(void* const* d_in, const int* in_sizes, int n_in,
                              void* d_out, int out_size, void* d_ws, size_t ws_size,
                              hipStream_t stream) {
  const int* x            = (const int*)d_in[0];
  const int* ei           = (const int*)d_in[1];   // int32 (JAX x64 disabled)
  const float* ncells     = (const float*)d_in[3];
  const float* emb        = (const float*)d_in[4];
  const float* W2         = (const float*)d_in[5];
  const float* b2         = (const float*)d_in[6];
  const float* W3         = (const float*)d_in[7];
  const float* b3         = (const float*)d_in[8];
  const float* W1         = (const float*)d_in[9];
  const float* b1         = (const float*)d_in[10];
  const float* Wp         = (const float*)d_in[11];
  const float* bp         = (const float*)d_in[12];
  float* dout = (float*)d_out;

  // workspace layout (~62 MB): accum first so the zeroing memset is tiny.
  char* w = (char*)d_ws;
  float* accum = (float*)w;                            // 2192 floats: num8, den8, xp128, SS2048
  float* num   = accum;
  float* den   = accum + 8;
  float* xp    = accum + 16;
  float* SSb   = accum + 144;
  float* dis   = accum + 2192;                         // N
  float2* dx   = (float2*)(dis + NN);                  // N float2 (dis, x-bits)
  int* offs    = (int*)(dx + NN);                      // N
  int* cnt     = offs + NN;                            // N
  int* adj     = cnt + NN;                             // E
  int* bsum    = adj + EE;                             // 256
  int* bscan   = bsum + 256;                           // 256
  float* M1    = (float*)(bscan + 256);                // 512
  __half2* out1h = (__half2*)(M1 + 512);               // N*32 half2 = 32 MB

  hipMemsetAsync(accum, 0, 2192 * sizeof(float), stream);

  k_count <<<512, 512, 0, stream>>>(ei, x, cnt, dis, dx);
  k_scanA <<<256, 256, 0, stream>>>(cnt, bsum);
  k_scanB <<<1, 256, 0, stream>>>(bsum, bscan);
  k_scanC <<<256, 256, 0, stream>>>(cnt, bscan, offs);
  k_fill2 <<<512, 512, 0, stream>>>(ei, offs, adj);
  k_m1    <<<1, 512, 0, stream>>>(emb, W2, M1);
  k_out1  <<<16384, 256, 0, stream>>>(adj, offs, cnt, dx, M1, b2, out1h);
  k_layer2<<<16384, 256, 0, stream>>>(adj, offs, cnt, dis, out1h, W3, b3, W1, b1, dout);
  k_num   <<<16384, 256, 0, stream>>>(adj, offs, cnt, dout + 8, num, den);
  k_ssden <<<1024, 256, 0, stream>>>(dout + 8, xp, SSb);
  k_final <<<1, 256, 0, stream>>>(accum, ncells, Wp, bp, dout);
}

// Round 6
// 441.484 us; speedup vs baseline: 2.0018x; 1.8837x over previous
//
#include <hip/hip_runtime.h>
#include <hip/hip_bf16.h>
#include <hip/hip_fp16.h>
#include <math.h>

#define NN 262144
#define EE 2097152
#define NPER 32768
#define EPG 262144   // edges per graph

typedef float4 f4;

// ---------------- pass 1: per-block (512 nodes of one graph) count in-degree from dst scan.
// Zero global atomics: LDS counters, coalesced writeout. Blocks of graph g pinned to XCD g (bid&7).
__global__ __launch_bounds__(512) void k_count(const int* __restrict__ ei, const int* __restrict__ x,
                                               int* __restrict__ cnt, float* __restrict__ dis,
                                               float2* __restrict__ dx) {
  __shared__ int cntl[512];
  int t = threadIdx.x;
  int bid = blockIdx.x;
  int g = bid & 7;            // graph == XCD (round-robin dispatch)
  int blk = bid >> 3;         // 0..63 within graph
  int lo = g * NPER + blk * 512;
  cntl[t] = 0;
  __syncthreads();
  const int4* dst4 = (const int4*)(ei + EE + (size_t)g * EPG);
#pragma unroll 4
  for (int j = 0; j < 128; ++j) {
    int4 d4 = dst4[j * 512 + t];
    if ((unsigned)(d4.x - lo) < 512u) atomicAdd(&cntl[d4.x - lo], 1);
    if ((unsigned)(d4.y - lo) < 512u) atomicAdd(&cntl[d4.y - lo], 1);
    if ((unsigned)(d4.z - lo) < 512u) atomicAdd(&cntl[d4.z - lo], 1);
    if ((unsigned)(d4.w - lo) < 512u) atomicAdd(&cntl[d4.w - lo], 1);
  }
  __syncthreads();
  int c = cntl[t];
  int n = lo + t;
  cnt[n] = c;
  float dn = rsqrtf((float)(c + 1));   // +1 self loop
  dis[n] = dn;
  dx[n] = make_float2(dn, __int_as_float(x[n]));
}

// ---------------- exclusive scan of cnt over N (3 kernels)
__global__ __launch_bounds__(256) void k_scanA(const int* __restrict__ cnt, int* __restrict__ bsum) {
  __shared__ int sm[256];
  int t = threadIdx.x;
  int base = blockIdx.x * 1024 + t * 4;
  int s = cnt[base] + cnt[base + 1] + cnt[base + 2] + cnt[base + 3];
  sm[t] = s;
  __syncthreads();
  for (int off = 128; off > 0; off >>= 1) {
    if (t < off) sm[t] += sm[t + off];
    __syncthreads();
  }
  if (t == 0) bsum[blockIdx.x] = sm[0];
}

__global__ __launch_bounds__(256) void k_scanB(const int* __restrict__ bsum, int* __restrict__ bscan) {
  __shared__ int sm[256];
  int t = threadIdx.x;
  int orig = bsum[t];
  sm[t] = orig;
  __syncthreads();
  for (int off = 1; off < 256; off <<= 1) {
    int v = (t >= off) ? sm[t - off] : 0;
    __syncthreads();
    sm[t] += v;
    __syncthreads();
  }
  bscan[t] = sm[t] - orig;  // exclusive
}

__global__ __launch_bounds__(256) void k_scanC(const int* __restrict__ cnt, const int* __restrict__ bscan,
                                               int* __restrict__ offs) {
  __shared__ int sm[256];
  int t = threadIdx.x;
  int base = blockIdx.x * 1024 + t * 4;
  int c0 = cnt[base], c1 = cnt[base + 1], c2 = cnt[base + 2], c3 = cnt[base + 3];
  int s = c0 + c1 + c2 + c3;
  sm[t] = s;
  __syncthreads();
  for (int off = 1; off < 256; off <<= 1) {
    int v = (t >= off) ? sm[t - off] : 0;
    __syncthreads();
    sm[t] += v;
    __syncthreads();
  }
  int ex = sm[t] - s + bscan[blockIdx.x];
  offs[base] = ex; offs[base + 1] = ex + c0; offs[base + 2] = ex + c0 + c1; offs[base + 3] = ex + c0 + c1 + c2;
}

// ---------------- pass 2: CSR fill. Block owns 512 dsts; LDS cursor; adj writes land in the
// block's exclusive ~16KB window -> L2 write-combined (no global atomics).
__global__ __launch_bounds__(512) void k_fill2(const int* __restrict__ ei, const int* __restrict__ offs,
                                               int* __restrict__ adj) {
  __shared__ int curl[512];
  int t = threadIdx.x;
  int bid = blockIdx.x;
  int g = bid & 7;
  int blk = bid >> 3;
  int lo = g * NPER + blk * 512;
  curl[t] = offs[lo + t];
  __syncthreads();
  const int4* src4 = (const int4*)(ei + (size_t)g * EPG);
  const int4* dst4 = (const int4*)(ei + EE + (size_t)g * EPG);
  for (int j = 0; j < 128; ++j) {
    int4 s4 = src4[j * 512 + t];
    int4 d4 = dst4[j * 512 + t];
    if ((unsigned)(d4.x - lo) < 512u) adj[atomicAdd(&curl[d4.x - lo], 1)] = s4.x;
    if ((unsigned)(d4.y - lo) < 512u) adj[atomicAdd(&curl[d4.y - lo], 1)] = s4.y;
    if ((unsigned)(d4.z - lo) < 512u) adj[atomicAdd(&curl[d4.z - lo], 1)] = s4.z;
    if ((unsigned)(d4.w - lo) < 512u) adj[atomicAdd(&curl[d4.w - lo], 1)] = s4.w;
  }
}

// ---------------- M1 = emb_w @ W2  (8x64)
__global__ void k_m1(const float* __restrict__ emb, const float* __restrict__ W2, float* __restrict__ M1) {
  int t = threadIdx.x;  // 512 threads
  int c = t >> 6, j = t & 63;
  float acc = 0.f;
  for (int k = 0; k < 64; ++k) acc += emb[c * 64 + k] * W2[k * 64 + j];
  M1[c * 64 + j] = acc;
}

// ---------------- out1h = fp16( dis[n] * relu(W8row@M1 + b2) ); W8row gathered from CSR.
// 16 threads/node; predicated 8-class accumulate + shfl reduce.
__global__ __launch_bounds__(256) void k_out1(const int* __restrict__ adj, const int* __restrict__ offs,
                                              const int* __restrict__ cnt, const float2* __restrict__ dx,
                                              const float* __restrict__ M1, const float* __restrict__ b2,
                                              __half2* __restrict__ out1h) {
  int tid = threadIdx.x;
  int bid = blockIdx.x;
  int swz = (bid & 7) * 2048 + (bid >> 3);    // XCD-local graph
  int node = swz * 16 + (tid >> 4);
  int t16 = tid & 15;
  float2 dxn = dx[node];
  float dn = dxn.x;
  int xc = __float_as_int(dxn.y);
  int off = offs[node], c = cnt[node];
  float wv[8] = {0.f, 0.f, 0.f, 0.f, 0.f, 0.f, 0.f, 0.f};
  for (int it = t16; it < c; it += 16) {
    int s = adj[off + it];
    float2 v = dx[s];
    int cls = __float_as_int(v.y);
#pragma unroll
    for (int k = 0; k < 8; ++k) wv[k] += (cls == k) ? v.x : 0.f;
  }
#pragma unroll
  for (int k = 0; k < 8; ++k) {
#pragma unroll
    for (int m = 1; m < 16; m <<= 1) wv[k] += __shfl_xor(wv[k], m);
    wv[k] = (wv[k] + ((k == xc) ? dn : 0.f)) * dn;   // + self (dis), scale by dis[d]
  }
  int j0 = t16 * 4;
  float o0 = b2[j0], o1 = b2[j0 + 1], o2 = b2[j0 + 2], o3 = b2[j0 + 3];
#pragma unroll
  for (int k = 0; k < 8; ++k) {
    f4 m = *(const f4*)&M1[k * 64 + j0];
    o0 += wv[k] * m.x; o1 += wv[k] * m.y; o2 += wv[k] * m.z; o3 += wv[k] * m.w;
  }
  __half2 h01 = __floats2half2_rn(fmaxf(o0, 0.f) * dn, fmaxf(o1, 0.f) * dn);
  __half2 h23 = __floats2half2_rn(fmaxf(o2, 0.f) * dn, fmaxf(o3, 0.f) * dn);
  size_t p = (size_t)node * 32 + t16 * 2;
  out1h[p] = h01;
  out1h[p + 1] = h23;
}

// ---------------- layer 2: CSR gather of prescaled fp16 out1 (4-way chunked), @W3+b3,relu,
// @W1+b1, softmax -> d_out
__global__ __launch_bounds__(256) void k_layer2(const int* __restrict__ adj, const int* __restrict__ offs,
                                                const int* __restrict__ cnt, const float* __restrict__ dis,
                                                const __half2* __restrict__ out1h,
                                                const float* __restrict__ W3, const float* __restrict__ b3,
                                                const float* __restrict__ W1, const float* __restrict__ b1,
                                                float* __restrict__ dout) {
  __shared__ float aggl[16 * 68];
  __shared__ float o2l[16 * 68];
  int tid = threadIdx.x;
  int bid = blockIdx.x;
  int swz = (bid & 7) * 2048 + (bid >> 3);
  int lane = tid & 63;
  int sub = lane >> 4, part = lane & 15;
  int ndl = ((tid >> 6) << 2) + sub;
  int node = swz * 16 + ndl;
  int j0 = part * 4;

  float dn = dis[node];
  int off = offs[node];
  int c = cnt[node];
  const __half2* sp = out1h + (size_t)node * 32 + part * 2;
  float2 f01 = __half22float2(sp[0]), f23 = __half22float2(sp[1]);
  float ax = f01.x, ay = f01.y, az = f23.x, aw = f23.y;   // self (prescaled)
  int it = 0;
  for (; it + 4 <= c; it += 4) {
    int s0 = adj[off + it], s1 = adj[off + it + 1], s2 = adj[off + it + 2], s3 = adj[off + it + 3];
    const __half2* p0 = out1h + (size_t)s0 * 32 + part * 2;
    const __half2* p1 = out1h + (size_t)s1 * 32 + part * 2;
    const __half2* p2 = out1h + (size_t)s2 * 32 + part * 2;
    const __half2* p3 = out1h + (size_t)s3 * 32 + part * 2;
    __half2 a0 = p0[0], c0 = p0[1], a1 = p1[0], c1 = p1[1];
    __half2 a2 = p2[0], c2 = p2[1], a3 = p3[0], c3 = p3[1];
    float2 u;
    u = __half22float2(a0); ax += u.x; ay += u.y;  u = __half22float2(c0); az += u.x; aw += u.y;
    u = __half22float2(a1); ax += u.x; ay += u.y;  u = __half22float2(c1); az += u.x; aw += u.y;
    u = __half22float2(a2); ax += u.x; ay += u.y;  u = __half22float2(c2); az += u.x; aw += u.y;
    u = __half22float2(a3); ax += u.x; ay += u.y;  u = __half22float2(c3); az += u.x; aw += u.y;
  }
  for (; it < c; ++it) {
    int s = adj[off + it];
    const __half2* hp = out1h + (size_t)s * 32 + part * 2;
    float2 g01 = __half22float2(hp[0]), g23 = __half22float2(hp[1]);
    ax += g01.x; ay += g01.y; az += g23.x; aw += g23.y;
  }
  f4 st; st.x = dn * ax; st.y = dn * ay; st.z = dn * az; st.w = dn * aw;
  *(f4*)&aggl[ndl * 68 + j0] = st;
  __syncthreads();

  // o2 = relu(agg @ W3 + b3)
  {
    int w = tid >> 6;
    int j = tid & 63;
    float bb = b3[j];
    float o0 = bb, o1 = bb, o2 = bb, o3 = bb;
    for (int k = 0; k < 64; ++k) {
      float wk = W3[k * 64 + j];
      o0 += aggl[(w * 4 + 0) * 68 + k] * wk;
      o1 += aggl[(w * 4 + 1) * 68 + k] * wk;
      o2 += aggl[(w * 4 + 2) * 68 + k] * wk;
      o3 += aggl[(w * 4 + 3) * 68 + k] * wk;
    }
    o2l[(w * 4 + 0) * 68 + j] = fmaxf(o0, 0.f);
    o2l[(w * 4 + 1) * 68 + j] = fmaxf(o1, 0.f);
    o2l[(w * 4 + 2) * 68 + j] = fmaxf(o2, 0.f);
    o2l[(w * 4 + 3) * 68 + j] = fmaxf(o3, 0.f);
  }
  __syncthreads();

  // s = o2 @ W1 + b1, softmax over 16 lanes
  int nd2 = tid >> 4, t16 = tid & 15;
  float sv = b1[t16];
  const float* o2p = &o2l[nd2 * 68];
  for (int j = 0; j < 64; ++j) sv += o2p[j] * W1[j * 16 + t16];
  float mx = sv;
#pragma unroll
  for (int m = 1; m < 16; m <<= 1) mx = fmaxf(mx, __shfl_xor(mx, m));
  float ex = expf(sv - mx);
  float sm = ex;
#pragma unroll
  for (int m = 1; m < 16; m <<= 1) sm += __shfl_xor(sm, m);
  dout[8 + (size_t)swz * 256 + tid] = ex / sm;
}

// ---------------- mincut num + den via CSR -> per-block partials (NO global atomics)
__global__ __launch_bounds__(256) void k_num(const int* __restrict__ adj, const int* __restrict__ offs,
                                             const int* __restrict__ cnt, const float* __restrict__ sb,
                                             float* __restrict__ numP, float* __restrict__ denP) {
  __shared__ float redn[16];
  __shared__ float redd[16];
  int tid = threadIdx.x;
  int bid = blockIdx.x;
  int swz = (bid & 7) * 2048 + (bid >> 3);
  int grp = tid >> 4, t16 = tid & 15;
  int node = swz * 16 + grp;
  int off = offs[node];
  int c = cnt[node];
  float sv = 0.f, sq = 0.f;
  int it = 0;
  for (; it + 4 <= c; it += 4) {
    int s0 = adj[off + it], s1 = adj[off + it + 1], s2 = adj[off + it + 2], s3 = adj[off + it + 3];
    float v0 = sb[(size_t)s0 * 16 + t16];
    float v1 = sb[(size_t)s1 * 16 + t16];
    float v2 = sb[(size_t)s2 * 16 + t16];
    float v3 = sb[(size_t)s3 * 16 + t16];
    sv += v0 + v1 + v2 + v3;
    sq += v0 * v0 + v1 * v1 + v2 * v2 + v3 * v3;
  }
  for (; it < c; ++it) {
    float v = sb[(size_t)adj[off + it] * 16 + t16];
    sv += v;
    sq += v * v;
  }
  float dot = sb[(size_t)node * 16 + t16] * sv;
#pragma unroll
  for (int m = 1; m < 16; m <<= 1) {
    dot += __shfl_xor(dot, m);
    sq  += __shfl_xor(sq, m);
  }
  if (t16 == 0) { redn[grp] = dot; redd[grp] = sq; }
  __syncthreads();
  if (tid == 0) {
    float a = 0.f, b = 0.f;
#pragma unroll
    for (int i = 0; i < 16; ++i) { a += redn[i]; b += redd[i]; }
    numP[swz] = a;
    denP[swz] = b;
  }
}

// ---------------- xp + SS per graph -> per-block partials (NO global atomics)
__global__ __launch_bounds__(256) void k_ssden(const float* __restrict__ sb,
                                               float* __restrict__ xpP, float* __restrict__ SSp) {
  __shared__ float sl[256 * 17];
  __shared__ float xpl[16];
  int t = threadIdx.x;
  int b = blockIdx.x;
  int t1 = t >> 4, t2 = t & 15;
  if (t < 16) xpl[t] = 0.f;
  int node = b * 256 + t;
  const f4* pr = (const f4*)&sb[(size_t)node * 16];
  f4 r0 = pr[0], r1 = pr[1], r2 = pr[2], r3 = pr[3];
  float* row = &sl[t * 17];
  row[0] = r0.x; row[1] = r0.y; row[2] = r0.z; row[3] = r0.w;
  row[4] = r1.x; row[5] = r1.y; row[6] = r1.z; row[7] = r1.w;
  row[8] = r2.x; row[9] = r2.y; row[10] = r2.z; row[11] = r2.w;
  row[12] = r3.x; row[13] = r3.y; row[14] = r3.z; row[15] = r3.w;
  __syncthreads();
  float ss = 0.f;
  for (int n = 0; n < 256; ++n) ss += sl[n * 17 + t1] * sl[n * 17 + t2];
  SSp[(size_t)b * 256 + t] = ss;
  float colsum = 0.f;
#pragma unroll
  for (int r = 0; r < 16; ++r) colsum += sl[(t1 * 16 + r) * 17 + t2];
  atomicAdd(&xpl[t2], colsum);           // LDS atomic (cheap)
  __syncthreads();
  if (t < 16) xpP[b * 16 + t] = xpl[t];
}

// ---------------- reduce partials into accum (8 blocks, one per graph)
__global__ __launch_bounds__(256) void k_red(const float* __restrict__ numP, const float* __restrict__ denP,
                                             const float* __restrict__ SSp, const float* __restrict__ xpP,
                                             float* __restrict__ accum) {
  __shared__ float r1[256], r2[256];
  int g = blockIdx.x, t = threadIdx.x;
  // SS: sum 128 block-partials (coalesced: 256 threads read contiguous 1KB per step)
  float acc = 0.f;
  for (int b = 0; b < 128; ++b) acc += SSp[((size_t)(g * 128 + b)) * 256 + t];
  accum[144 + g * 256 + t] = acc;
  // num/den: 2048 partials each
  float a = 0.f, d = 0.f;
  for (int i = 0; i < 8; ++i) {
    a += numP[g * 2048 + i * 256 + t];
    d += denP[g * 2048 + i * 256 + t];
  }
  r1[t] = a; r2[t] = d;
  __syncthreads();
  for (int off = 128; off > 0; off >>= 1) {
    if (t < off) { r1[t] += r1[t + off]; r2[t] += r2[t + off]; }
    __syncthreads();
  }
  if (t == 0) { accum[g] = r1[0]; accum[8 + g] = r2[0]; }
  // xp: 128 partials x 16
  if (t < 16) {
    float s = 0.f;
    for (int b = 0; b < 128; ++b) s += xpP[(g * 128 + b) * 16 + t];
    accum[16 + g * 16 + t] = s;
  }
}

// ---------------- scalars: mc1, o1, pred
__global__ __launch_bounds__(256) void k_final(const float* __restrict__ accum, const float* __restrict__ ncells,
                                               const float* __restrict__ Wp, const float* __restrict__ bp,
                                               float* __restrict__ dout) {
  __shared__ float red[256];
  __shared__ float bc;
  int t = threadIdx.x;
  const float* num = accum;
  const float* den = accum + 8;
  const float* xp  = accum + 16;
  const float* SSb = accum + 144;
  float o1s = 0.f;
  for (int g = 0; g < 8; ++g) {
    float v = SSb[g * 256 + t];
    red[t] = v * v;
    __syncthreads();
    for (int off = 128; off > 0; off >>= 1) {
      if (t < off) red[t] += red[t + off];
      __syncthreads();
    }
    if (t == 0) bc = sqrtf(red[0]);
    __syncthreads();
    float nrm = bc;
    float diag = ((t >> 4) == (t & 15)) ? 0.25f : 0.f;  // I/sqrt(16)
    float dv = v / nrm - diag;
    red[t] = dv * dv;
    __syncthreads();
    for (int off = 128; off > 0; off >>= 1) {
      if (t < off) red[t] += red[t + off];
      __syncthreads();
    }
    if (t == 0) o1s += sqrtf(red[0]);
    __syncthreads();
  }
  if (t == 0) {
    dout[8 + (size_t)NN * 16 + 1] = o1s / 8.f;
    float m = 0.f;
    for (int g = 0; g < 8; ++g) m += -num[g] / den[g];
    dout[8 + (size_t)NN * 16] = m / 8.f;
  }
  if (t < 8) {
    float p = bp[0];
    for (int k = 0; k < 16; ++k) p += (xp[t * 16 + k] / ncells[t]) * Wp[k];
    dout[t] = p;
  }
}

extern "C" void kernel_launch(void* const* d_in, const int* in_sizes, int n_in,
                              void* d_out, int out_size, void* d_ws, size_t ws_size,
                              hipStream_t stream) {
  const int* x            = (const int*)d_in[0];
  const int* ei           = (const int*)d_in[1];   // int32 (JAX x64 disabled)
  const float* ncells     = (const float*)d_in[3];
  const float* emb        = (const float*)d_in[4];
  const float* W2         = (const float*)d_in[5];
  const float* b2         = (const float*)d_in[6];
  const float* W3         = (const float*)d_in[7];
  const float* b3         = (const float*)d_in[8];
  const float* W1         = (const float*)d_in[9];
  const float* b1         = (const float*)d_in[10];
  const float* Wp         = (const float*)d_in[11];
  const float* bp         = (const float*)d_in[12];
  float* dout = (float*)d_out;

  // workspace layout (~64 MB); every cell is fully written before read each launch (no memset).
  char* w = (char*)d_ws;
  float* accum = (float*)w;                            // 2192: num8, den8, xp128, SS2048
  float* dis   = accum + 2192;                         // N
  float2* dx   = (float2*)(dis + NN);                  // N float2 (dis, x-bits)
  int* offs    = (int*)(dx + NN);                      // N
  int* cnt     = offs + NN;                            // N
  int* adj     = cnt + NN;                             // E
  int* bsum    = adj + EE;                             // 256
  int* bscan   = bsum + 256;                           // 256
  float* M1    = (float*)(bscan + 256);                // 512
  __half2* out1h = (__half2*)(M1 + 512);               // N*32 half2 = 32 MB
  float* numP  = (float*)(out1h + (size_t)NN * 32);    // 16384
  float* denP  = numP + 16384;                         // 16384
  float* SSp   = denP + 16384;                         // 1024*256
  float* xpP   = SSp + 1024 * 256;                     // 1024*16

  k_count <<<512, 512, 0, stream>>>(ei, x, cnt, dis, dx);
  k_scanA <<<256, 256, 0, stream>>>(cnt, bsum);
  k_scanB <<<1, 256, 0, stream>>>(bsum, bscan);
  k_scanC <<<256, 256, 0, stream>>>(cnt, bscan, offs);
  k_fill2 <<<512, 512, 0, stream>>>(ei, offs, adj);
  k_m1    <<<1, 512, 0, stream>>>(emb, W2, M1);
  k_out1  <<<16384, 256, 0, stream>>>(adj, offs, cnt, dx, M1, b2, out1h);
  k_layer2<<<16384, 256, 0, stream>>>(adj, offs, cnt, dis, out1h, W3, b3, W1, b1, dout);
  k_num   <<<16384, 256, 0, stream>>>(adj, offs, cnt, dout + 8, numP, denP);
  k_ssden <<<1024, 256, 0, stream>>>(dout + 8, xpP, SSp);
  k_red   <<<8, 256, 0, stream>>>(numP, denP, SSp, xpP, accum);
  k_final <<<1, 256, 0, stream>>>(accum, ncells, Wp, bp, dout);
}

// Round 7
// 365.256 us; speedup vs baseline: 2.4196x; 1.2087x over previous
//
#include <hip/hip_runtime.h>
#include <hip/hip_bf16.h>
#include <hip/hip_fp16.h>
#include <math.h>

#define NN 262144
#define EE 2097152
#define NPER 32768
#define EPG 262144   // edges per graph

typedef float4 f4;
typedef __attribute__((ext_vector_type(4))) float f32x4;
typedef __attribute__((ext_vector_type(8))) _Float16 half8;
typedef __attribute__((ext_vector_type(4))) _Float16 half4;

// ---------------- pass 1: per-block (512 nodes of one graph) count in-degree from dst scan.
__global__ __launch_bounds__(512) void k_count(const int* __restrict__ ei, const int* __restrict__ x,
                                               int* __restrict__ cnt, float* __restrict__ dis,
                                               float2* __restrict__ dx) {
  __shared__ int cntl[512];
  int t = threadIdx.x;
  int bid = blockIdx.x;
  int g = bid & 7;            // graph == XCD (round-robin dispatch)
  int blk = bid >> 3;         // 0..63 within graph
  int lo = g * NPER + blk * 512;
  cntl[t] = 0;
  __syncthreads();
  const int4* dst4 = (const int4*)(ei + EE + (size_t)g * EPG);
#pragma unroll 4
  for (int j = 0; j < 128; ++j) {
    int4 d4 = dst4[j * 512 + t];
    if ((unsigned)(d4.x - lo) < 512u) atomicAdd(&cntl[d4.x - lo], 1);
    if ((unsigned)(d4.y - lo) < 512u) atomicAdd(&cntl[d4.y - lo], 1);
    if ((unsigned)(d4.z - lo) < 512u) atomicAdd(&cntl[d4.z - lo], 1);
    if ((unsigned)(d4.w - lo) < 512u) atomicAdd(&cntl[d4.w - lo], 1);
  }
  __syncthreads();
  int c = cntl[t];
  int n = lo + t;
  cnt[n] = c;
  float dn = rsqrtf((float)(c + 1));   // +1 self loop
  dis[n] = dn;
  dx[n] = make_float2(dn, __int_as_float(x[n]));
}

// ---------------- exclusive scan of cnt over N (3 kernels)
__global__ __launch_bounds__(256) void k_scanA(const int* __restrict__ cnt, int* __restrict__ bsum) {
  __shared__ int sm[256];
  int t = threadIdx.x;
  int base = blockIdx.x * 1024 + t * 4;
  int s = cnt[base] + cnt[base + 1] + cnt[base + 2] + cnt[base + 3];
  sm[t] = s;
  __syncthreads();
  for (int off = 128; off > 0; off >>= 1) {
    if (t < off) sm[t] += sm[t + off];
    __syncthreads();
  }
  if (t == 0) bsum[blockIdx.x] = sm[0];
}

__global__ __launch_bounds__(256) void k_scanB(const int* __restrict__ bsum, int* __restrict__ bscan) {
  __shared__ int sm[256];
  int t = threadIdx.x;
  int orig = bsum[t];
  sm[t] = orig;
  __syncthreads();
  for (int off = 1; off < 256; off <<= 1) {
    int v = (t >= off) ? sm[t - off] : 0;
    __syncthreads();
    sm[t] += v;
    __syncthreads();
  }
  bscan[t] = sm[t] - orig;  // exclusive
}

__global__ __launch_bounds__(256) void k_scanC(const int* __restrict__ cnt, const int* __restrict__ bscan,
                                               int* __restrict__ offs) {
  __shared__ int sm[256];
  int t = threadIdx.x;
  int base = blockIdx.x * 1024 + t * 4;
  int c0 = cnt[base], c1 = cnt[base + 1], c2 = cnt[base + 2], c3 = cnt[base + 3];
  int s = c0 + c1 + c2 + c3;
  sm[t] = s;
  __syncthreads();
  for (int off = 1; off < 256; off <<= 1) {
    int v = (t >= off) ? sm[t - off] : 0;
    __syncthreads();
    sm[t] += v;
    __syncthreads();
  }
  int ex = sm[t] - s + bscan[blockIdx.x];
  offs[base] = ex; offs[base + 1] = ex + c0; offs[base + 2] = ex + c0 + c1; offs[base + 3] = ex + c0 + c1 + c2;
}

// ---------------- pass 2: CSR fill (LDS cursors, no global atomics)
__global__ __launch_bounds__(512) void k_fill2(const int* __restrict__ ei, const int* __restrict__ offs,
                                               int* __restrict__ adj) {
  __shared__ int curl[512];
  int t = threadIdx.x;
  int bid = blockIdx.x;
  int g = bid & 7;
  int blk = bid >> 3;
  int lo = g * NPER + blk * 512;
  curl[t] = offs[lo + t];
  __syncthreads();
  const int4* src4 = (const int4*)(ei + (size_t)g * EPG);
  const int4* dst4 = (const int4*)(ei + EE + (size_t)g * EPG);
  for (int j = 0; j < 128; ++j) {
    int4 s4 = src4[j * 512 + t];
    int4 d4 = dst4[j * 512 + t];
    if ((unsigned)(d4.x - lo) < 512u) adj[atomicAdd(&curl[d4.x - lo], 1)] = s4.x;
    if ((unsigned)(d4.y - lo) < 512u) adj[atomicAdd(&curl[d4.y - lo], 1)] = s4.y;
    if ((unsigned)(d4.z - lo) < 512u) adj[atomicAdd(&curl[d4.z - lo], 1)] = s4.z;
    if ((unsigned)(d4.w - lo) < 512u) adj[atomicAdd(&curl[d4.w - lo], 1)] = s4.w;
  }
}

// ---------------- M1 = emb_w @ W2  (8x64)
__global__ void k_m1(const float* __restrict__ emb, const float* __restrict__ W2, float* __restrict__ M1) {
  int t = threadIdx.x;  // 512 threads
  int c = t >> 6, j = t & 63;
  float acc = 0.f;
  for (int k = 0; k < 64; ++k) acc += emb[c * 64 + k] * W2[k * 64 + j];
  M1[c * 64 + j] = acc;
}

// ---------------- pack W3, W1 into f16 MFMA B-fragment layout.
// B-frag (16x16x32): lane l holds col=l&15, k=kk*32+(l>>4)*8+i  (i=0..7 contiguous)
__global__ __launch_bounds__(256) void k_pack(const float* __restrict__ W3, const float* __restrict__ W1,
                                              _Float16* __restrict__ W3p, _Float16* __restrict__ W1p) {
  int t = blockIdx.x * 256 + threadIdx.x;   // 5120 total
  if (t < 4096) {
    int jt = t >> 10, kk = (t >> 9) & 1, l = (t >> 3) & 63, i = t & 7;
    int k = kk * 32 + (l >> 4) * 8 + i;
    int j = jt * 16 + (l & 15);
    W3p[t] = (_Float16)W3[k * 64 + j];
  } else if (t < 5120) {
    int q = t - 4096;
    int kk = q >> 9, l = (q >> 3) & 63, i = q & 7;
    int k = kk * 32 + (l >> 4) * 8 + i;
    int c = l & 15;
    W1p[q] = (_Float16)W1[k * 16 + c];
  }
}

// ---------------- out1h = fp16( dis[n] * relu(W8row@M1 + b2) ); W8row gathered from CSR.
__global__ __launch_bounds__(256) void k_out1(const int* __restrict__ adj, const int* __restrict__ offs,
                                              const int* __restrict__ cnt, const float2* __restrict__ dx,
                                              const float* __restrict__ M1, const float* __restrict__ b2,
                                              __half2* __restrict__ out1h) {
  int tid = threadIdx.x;
  int bid = blockIdx.x;
  int swz = (bid & 7) * 2048 + (bid >> 3);    // XCD-local graph
  int node = swz * 16 + (tid >> 4);
  int t16 = tid & 15;
  float2 dxn = dx[node];
  float dn = dxn.x;
  int xc = __float_as_int(dxn.y);
  int off = offs[node], c = cnt[node];
  float wv[8] = {0.f, 0.f, 0.f, 0.f, 0.f, 0.f, 0.f, 0.f};
  for (int it = t16; it < c; it += 16) {
    int s = adj[off + it];
    float2 v = dx[s];
    int cls = __float_as_int(v.y);
#pragma unroll
    for (int k = 0; k < 8; ++k) wv[k] += (cls == k) ? v.x : 0.f;
  }
#pragma unroll
  for (int k = 0; k < 8; ++k) {
#pragma unroll
    for (int m = 1; m < 16; m <<= 1) wv[k] += __shfl_xor(wv[k], m);
    wv[k] = (wv[k] + ((k == xc) ? dn : 0.f)) * dn;   // + self (dis), scale by dis[d]
  }
  int j0 = t16 * 4;
  float o0 = b2[j0], o1 = b2[j0 + 1], o2 = b2[j0 + 2], o3 = b2[j0 + 3];
#pragma unroll
  for (int k = 0; k < 8; ++k) {
    f4 m = *(const f4*)&M1[k * 64 + j0];
    o0 += wv[k] * m.x; o1 += wv[k] * m.y; o2 += wv[k] * m.z; o3 += wv[k] * m.w;
  }
  __half2 h01 = __floats2half2_rn(fmaxf(o0, 0.f) * dn, fmaxf(o1, 0.f) * dn);
  __half2 h23 = __floats2half2_rn(fmaxf(o2, 0.f) * dn, fmaxf(o3, 0.f) * dn);
  size_t p = (size_t)node * 32 + t16 * 2;
  out1h[p] = h01;
  out1h[p + 1] = h23;
}

// ---------------- layer 2: CSR gather + MFMA(W3) + relu + MFMA(W1) + softmax -> d_out
__global__ __launch_bounds__(256) void k_layer2(const int* __restrict__ adj, const int* __restrict__ offs,
                                                const int* __restrict__ cnt, const float* __restrict__ dis,
                                                const __half2* __restrict__ out1h,
                                                const _Float16* __restrict__ W3p, const float* __restrict__ b3,
                                                const _Float16* __restrict__ W1p, const float* __restrict__ b1,
                                                float* __restrict__ dout) {
  __shared__ _Float16 aggh[16 * 64];   // [node][k] f16, XOR-swizzled rows (2 KB)
  __shared__ _Float16 o2h[16 * 64];    // [node][j] f16, XOR-swizzled rows (2 KB)
  int tid = threadIdx.x;
  int bid = blockIdx.x;
  int swz = (bid & 7) * 2048 + (bid >> 3);
  int lane = tid & 63;
  int w = tid >> 6;                    // wave id 0..3
  int sub = lane >> 4, part = lane & 15;
  int ndl = (w << 2) + sub;            // node-local 0..15
  int node = swz * 16 + ndl;

  // phase 1: agg = dn * sum(out1h[self] + out1h[neighbors])  (16 lanes x 4 cols per node)
  float dn = dis[node];
  int off = offs[node];
  int c = cnt[node];
  const __half2* sp = out1h + (size_t)node * 32 + part * 2;
  float2 f01 = __half22float2(sp[0]), f23 = __half22float2(sp[1]);
  float ax = f01.x, ay = f01.y, az = f23.x, aw = f23.y;   // self (prescaled)
  int it = 0;
  for (; it + 4 <= c; it += 4) {
    int s0 = adj[off + it], s1 = adj[off + it + 1], s2 = adj[off + it + 2], s3 = adj[off + it + 3];
    const __half2* p0 = out1h + (size_t)s0 * 32 + part * 2;
    const __half2* p1 = out1h + (size_t)s1 * 32 + part * 2;
    const __half2* p2 = out1h + (size_t)s2 * 32 + part * 2;
    const __half2* p3 = out1h + (size_t)s3 * 32 + part * 2;
    __half2 a0 = p0[0], c0 = p0[1], a1 = p1[0], c1 = p1[1];
    __half2 a2 = p2[0], c2 = p2[1], a3 = p3[0], c3 = p3[1];
    float2 u;
    u = __half22float2(a0); ax += u.x; ay += u.y;  u = __half22float2(c0); az += u.x; aw += u.y;
    u = __half22float2(a1); ax += u.x; ay += u.y;  u = __half22float2(c1); az += u.x; aw += u.y;
    u = __half22float2(a2); ax += u.x; ay += u.y;  u = __half22float2(c2); az += u.x; aw += u.y;
    u = __half22float2(a3); ax += u.x; ay += u.y;  u = __half22float2(c3); az += u.x; aw += u.y;
  }
  for (; it < c; ++it) {
    int s = adj[off + it];
    const __half2* hp = out1h + (size_t)s * 32 + part * 2;
    float2 g01 = __half22float2(hp[0]), g23 = __half22float2(hp[1]);
    ax += g01.x; ay += g01.y; az += g23.x; aw += g23.y;
  }
  // store agg row (f16) swizzled: byte = node*128 + part*8, ^= (node&7)<<4
  {
    half4 hv = { (_Float16)(dn * ax), (_Float16)(dn * ay), (_Float16)(dn * az), (_Float16)(dn * aw) };
    int byte = (ndl * 128 + part * 8) ^ ((ndl & 7) << 4);
    *(half4*)((char*)aggh + byte) = hv;
  }
  __syncthreads();

  // phase 3a: o2 = relu(agg @ W3 + b3), wave w owns W3 cols [16w,16w+16)
  f32x4 acc = {0.f, 0.f, 0.f, 0.f};
#pragma unroll
  for (int kk = 0; kk < 2; ++kk) {
    int row = lane & 15;
    int abyte = (row * 128 + kk * 64 + (lane >> 4) * 16) ^ ((row & 7) << 4);
    half8 afrag = *(const half8*)((const char*)aggh + abyte);
    half8 bfrag = *(const half8*)&W3p[((w * 2 + kk) * 64 + lane) * 8];
    acc = __builtin_amdgcn_mfma_f32_16x16x32_f16(afrag, bfrag, acc, 0, 0, 0);
  }
  {
    int colj = w * 16 + (lane & 15);
    float b3v = b3[colj];
#pragma unroll
    for (int r = 0; r < 4; ++r) {
      int nrow = (lane >> 4) * 4 + r;                    // node 0..15
      _Float16 hv = (_Float16)fmaxf(acc[r] + b3v, 0.f);
      int byte = (nrow * 128 + colj * 2) ^ ((nrow & 7) << 4);
      *(_Float16*)((char*)o2h + byte) = hv;
    }
  }
  __syncthreads();

  // phase 3b: s = o2 @ W1 + b1 (each wave computes full 16x16; wave w stores node%4==w rows)
  f32x4 acc2 = {0.f, 0.f, 0.f, 0.f};
#pragma unroll
  for (int kk = 0; kk < 2; ++kk) {
    int row = lane & 15;
    int abyte = (row * 128 + kk * 64 + (lane >> 4) * 16) ^ ((row & 7) << 4);
    half8 afrag = *(const half8*)((const char*)o2h + abyte);
    half8 bfrag = *(const half8*)&W1p[(kk * 64 + lane) * 8];
    acc2 = __builtin_amdgcn_mfma_f32_16x16x32_f16(afrag, bfrag, acc2, 0, 0, 0);
  }
  {
    float sv = acc2[w] + b1[lane & 15];                  // this wave's reg r=w: node=(lane>>4)*4+w
    float mx = sv;
#pragma unroll
    for (int m = 1; m < 16; m <<= 1) mx = fmaxf(mx, __shfl_xor(mx, m));
    float ex = expf(sv - mx);
    float sm = ex;
#pragma unroll
    for (int m = 1; m < 16; m <<= 1) sm += __shfl_xor(sm, m);
    int nrow = (lane >> 4) * 4 + w;
    dout[8 + (size_t)swz * 256 + nrow * 16 + (lane & 15)] = ex / sm;
  }
}

// ---------------- mincut num + den via CSR -> per-block partials (NO global atomics)
__global__ __launch_bounds__(256) void k_num(const int* __restrict__ adj, const int* __restrict__ offs,
                                             const int* __restrict__ cnt, const float* __restrict__ sb,
                                             float* __restrict__ numP, float* __restrict__ denP) {
  __shared__ float redn[16];
  __shared__ float redd[16];
  int tid = threadIdx.x;
  int bid = blockIdx.x;
  int swz = (bid & 7) * 2048 + (bid >> 3);
  int grp = tid >> 4, t16 = tid & 15;
  int node = swz * 16 + grp;
  int off = offs[node];
  int c = cnt[node];
  float sv = 0.f, sq = 0.f;
  int it = 0;
  for (; it + 4 <= c; it += 4) {
    int s0 = adj[off + it], s1 = adj[off + it + 1], s2 = adj[off + it + 2], s3 = adj[off + it + 3];
    float v0 = sb[(size_t)s0 * 16 + t16];
    float v1 = sb[(size_t)s1 * 16 + t16];
    float v2 = sb[(size_t)s2 * 16 + t16];
    float v3 = sb[(size_t)s3 * 16 + t16];
    sv += v0 + v1 + v2 + v3;
    sq += v0 * v0 + v1 * v1 + v2 * v2 + v3 * v3;
  }
  for (; it < c; ++it) {
    float v = sb[(size_t)adj[off + it] * 16 + t16];
    sv += v;
    sq += v * v;
  }
  float dot = sb[(size_t)node * 16 + t16] * sv;
#pragma unroll
  for (int m = 1; m < 16; m <<= 1) {
    dot += __shfl_xor(dot, m);
    sq  += __shfl_xor(sq, m);
  }
  if (t16 == 0) { redn[grp] = dot; redd[grp] = sq; }
  __syncthreads();
  if (tid == 0) {
    float a = 0.f, b = 0.f;
#pragma unroll
    for (int i = 0; i < 16; ++i) { a += redn[i]; b += redd[i]; }
    numP[swz] = a;
    denP[swz] = b;
  }
}

// ---------------- xp + SS per graph -> per-block partials (NO global atomics)
__global__ __launch_bounds__(256) void k_ssden(const float* __restrict__ sb,
                                               float* __restrict__ xpP, float* __restrict__ SSp) {
  __shared__ float sl[256 * 17];
  __shared__ float xpl[16];
  int t = threadIdx.x;
  int b = blockIdx.x;
  int t1 = t >> 4, t2 = t & 15;
  if (t < 16) xpl[t] = 0.f;
  int node = b * 256 + t;
  const f4* pr = (const f4*)&sb[(size_t)node * 16];
  f4 r0 = pr[0], r1 = pr[1], r2 = pr[2], r3 = pr[3];
  float* row = &sl[t * 17];
  row[0] = r0.x; row[1] = r0.y; row[2] = r0.z; row[3] = r0.w;
  row[4] = r1.x; row[5] = r1.y; row[6] = r1.z; row[7] = r1.w;
  row[8] = r2.x; row[9] = r2.y; row[10] = r2.z; row[11] = r2.w;
  row[12] = r3.x; row[13] = r3.y; row[14] = r3.z; row[15] = r3.w;
  __syncthreads();
  float ss = 0.f;
  for (int n = 0; n < 256; ++n) ss += sl[n * 17 + t1] * sl[n * 17 + t2];
  SSp[(size_t)b * 256 + t] = ss;
  float colsum = 0.f;
#pragma unroll
  for (int r = 0; r < 16; ++r) colsum += sl[(t1 * 16 + r) * 17 + t2];
  atomicAdd(&xpl[t2], colsum);           // LDS atomic (cheap)
  __syncthreads();
  if (t < 16) xpP[b * 16 + t] = xpl[t];
}

// ---------------- reduce partials into accum + per-graph o1 (8 blocks, one per graph)
// accum layout: [num 8][den 8][xp 128][o1g 8]  (152 floats)
__global__ __launch_bounds__(256) void k_red(const float* __restrict__ numP, const float* __restrict__ denP,
                                             const float* __restrict__ SSp, const float* __restrict__ xpP,
                                             float* __restrict__ accum) {
  __shared__ float r1[256], r2[256];
  __shared__ float bc;
  int g = blockIdx.x, t = threadIdx.x;
  // SS element t of graph g: sum 128 block-partials
  float acc = 0.f;
  for (int b = 0; b < 128; ++b) acc += SSp[((size_t)(g * 128 + b)) * 256 + t];
  // num/den: 2048 partials each
  float a = 0.f, d = 0.f;
  for (int i = 0; i < 8; ++i) {
    a += numP[g * 2048 + i * 256 + t];
    d += denP[g * 2048 + i * 256 + t];
  }
  r1[t] = a; r2[t] = d;
  __syncthreads();
  for (int off = 128; off > 0; off >>= 1) {
    if (t < off) { r1[t] += r1[t + off]; r2[t] += r2[t + off]; }
    __syncthreads();
  }
  if (t == 0) { accum[g] = r1[0]; accum[8 + g] = r2[0]; }
  // xp: 128 partials x 16
  if (t < 16) {
    float s = 0.f;
    for (int b = 0; b < 128; ++b) s += xpP[(g * 128 + b) * 16 + t];
    accum[16 + g * 16 + t] = s;
  }
  __syncthreads();
  // o1 for this graph: ||SS||_F, then ||SS/||SS|| - I/4||_F
  r1[t] = acc * acc;
  __syncthreads();
  for (int off = 128; off > 0; off >>= 1) {
    if (t < off) r1[t] += r1[t + off];
    __syncthreads();
  }
  if (t == 0) bc = sqrtf(r1[0]);
  __syncthreads();
  float dv = acc / bc - (((t >> 4) == (t & 15)) ? 0.25f : 0.f);
  r1[t] = dv * dv;
  __syncthreads();
  for (int off = 128; off > 0; off >>= 1) {
    if (t < off) r1[t] += r1[t + off];
    __syncthreads();
  }
  if (t == 0) accum[144 + g] = sqrtf(r1[0]);
}

// ---------------- scalars: mc1, o1, pred (tiny)
__global__ __launch_bounds__(64) void k_final(const float* __restrict__ accum, const float* __restrict__ ncells,
                                              const float* __restrict__ Wp, const float* __restrict__ bp,
                                              float* __restrict__ dout) {
  int t = threadIdx.x;
  const float* num = accum;
  const float* den = accum + 8;
  const float* xp  = accum + 16;
  const float* o1g = accum + 144;
  if (t == 0) {
    float m = 0.f, o = 0.f;
    for (int g = 0; g < 8; ++g) { m += -num[g] / den[g]; o += o1g[g]; }
    dout[8 + (size_t)NN * 16] = m / 8.f;
    dout[8 + (size_t)NN * 16 + 1] = o / 8.f;
  }
  if (t < 8) {
    float p = bp[0];
    for (int k = 0; k < 16; ++k) p += (xp[t * 16 + k] / ncells[t]) * Wp[k];
    dout[t] = p;
  }
}

extern "C" void kernel_launch(void* const* d_in, const int* in_sizes, int n_in,
                              void* d_out, int out_size, void* d_ws, size_t ws_size,
                              hipStream_t stream) {
  const int* x            = (const int*)d_in[0];
  const int* ei           = (const int*)d_in[1];   // int32 (JAX x64 disabled)
  const float* ncells     = (const float*)d_in[3];
  const float* emb        = (const float*)d_in[4];
  const float* W2         = (const float*)d_in[5];
  const float* b2         = (const float*)d_in[6];
  const float* W3         = (const float*)d_in[7];
  const float* b3         = (const float*)d_in[8];
  const float* W1         = (const float*)d_in[9];
  const float* b1         = (const float*)d_in[10];
  const float* Wp         = (const float*)d_in[11];
  const float* bp         = (const float*)d_in[12];
  float* dout = (float*)d_out;

  // workspace layout; every cell fully written before read each launch (no memset needed).
  char* w = (char*)d_ws;
  float* accum = (float*)w;                            // 152: num8, den8, xp128, o1g8 (pad to 160)
  float* dis   = accum + 160;                          // N
  float2* dx   = (float2*)(dis + NN);                  // N float2 (dis, x-bits)
  int* offs    = (int*)(dx + NN);                      // N
  int* cnt     = offs + NN;                            // N
  int* adj     = cnt + NN;                             // E
  int* bsum    = adj + EE;                             // 256
  int* bscan   = bsum + 256;                           // 256
  float* M1    = (float*)(bscan + 256);                // 512
  _Float16* W3p = (_Float16*)(M1 + 512);               // 4096 halves
  _Float16* W1p = W3p + 4096;                          // 1024 halves
  __half2* out1h = (__half2*)(W1p + 1024);             // N*32 half2 = 32 MB
  float* numP  = (float*)(out1h + (size_t)NN * 32);    // 16384
  float* denP  = numP + 16384;                         // 16384
  float* SSp   = denP + 16384;                         // 1024*256
  float* xpP   = SSp + 1024 * 256;                     // 1024*16

  k_count <<<512, 512, 0, stream>>>(ei, x, cnt, dis, dx);
  k_scanA <<<256, 256, 0, stream>>>(cnt, bsum);
  k_scanB <<<1, 256, 0, stream>>>(bsum, bscan);
  k_scanC <<<256, 256, 0, stream>>>(cnt, bscan, offs);
  k_fill2 <<<512, 512, 0, stream>>>(ei, offs, adj);
  k_m1    <<<1, 512, 0, stream>>>(emb, W2, M1);
  k_pack  <<<20, 256, 0, stream>>>(W3, W1, W3p, W1p);
  k_out1  <<<16384, 256, 0, stream>>>(adj, offs, cnt, dx, M1, b2, out1h);
  k_layer2<<<16384, 256, 0, stream>>>(adj, offs, cnt, dis, out1h, W3p, b3, W1p, b1, dout);
  k_num   <<<16384, 256, 0, stream>>>(adj, offs, cnt, dout + 8, numP, denP);
  k_ssden <<<1024, 256, 0, stream>>>(dout + 8, xpP, SSp);
  k_red   <<<8, 256, 0, stream>>>(numP, denP, SSp, xpP, accum);
  k_final <<<1, 64, 0, stream>>>(accum, ncells, Wp, bp, dout);
}

// Round 8
// 269.934 us; speedup vs baseline: 3.2740x; 1.3531x over previous
//
#include <hip/hip_runtime.h>
#include <hip/hip_bf16.h>
#include <hip/hip_fp16.h>
#include <math.h>

#define NN 262144
#define EE 2097152
#define NPER 32768
#define EPG 262144   // edges per graph
#define EMAX 5120    // max edges per 512-node window (mean 4096, std 63; 16 sigma pad)

typedef float4 f4;
typedef __attribute__((ext_vector_type(4))) float f32x4;
typedef __attribute__((ext_vector_type(8))) _Float16 half8;
typedef __attribute__((ext_vector_type(4))) _Float16 half4;

// ---------------- binning pass 1: histogram of dst-windows per (graph, 4096-edge chunk)
__global__ __launch_bounds__(256) void k_hist(const int* __restrict__ ei, int* __restrict__ histT) {
  __shared__ int histl[64];
  int t = threadIdx.x;
  int bid = blockIdx.x;
  int g = bid & 7, c = bid >> 3;
  if (t < 64) histl[t] = 0;
  __syncthreads();
  int gN = g * NPER;
  const int4* dst4 = (const int4*)(ei + EE + (size_t)g * EPG + c * 4096);
#pragma unroll
  for (int j = 0; j < 4; ++j) {
    int4 d4 = dst4[j * 256 + t];
    atomicAdd(&histl[(d4.x - gN) >> 9], 1);
    atomicAdd(&histl[(d4.y - gN) >> 9], 1);
    atomicAdd(&histl[(d4.z - gN) >> 9], 1);
    atomicAdd(&histl[(d4.w - gN) >> 9], 1);
  }
  __syncthreads();
  if (t < 64) histT[((size_t)g * 64 + t) * 64 + c] = histl[t];   // [g][w][c]
}

// ---------------- binning pass 2: per-window totals + exact scatter bases (1 wave per graph)
__global__ __launch_bounds__(64) void k_hscan(const int* __restrict__ histT, int* __restrict__ winOff,
                                              int* __restrict__ winCnt, int* __restrict__ baseB) {
  int g = blockIdx.x, w = threadIdx.x;   // 64 threads = 64 windows
  const int* hrow = histT + ((size_t)g * 64 + w) * 64;
  int tot = 0;
#pragma unroll
  for (int c = 0; c < 64; ++c) tot += hrow[c];
  // exclusive scan of tot across the wave
  int incl = tot;
#pragma unroll
  for (int o = 1; o < 64; o <<= 1) {
    int u = __shfl_up(incl, o);
    if (w >= o) incl += u;
  }
  int excl = incl - tot;
  int base = g * EPG + excl;
  winOff[g * 64 + w] = base;
  winCnt[g * 64 + w] = tot;
  int run = base;
  for (int c = 0; c < 64; ++c) {            // baseB in [g][c][w] layout (coalesced writes per c)
    baseB[((size_t)g * 64 + c) * 64 + w] = run;
    run += hrow[c];
  }
}

// ---------------- binning pass 3: scatter edges into exact window bins (LDS cursors only)
__global__ __launch_bounds__(256) void k_scat(const int* __restrict__ ei, const int* __restrict__ baseB,
                                              int* __restrict__ binned) {
  __shared__ int curl[64];
  int t = threadIdx.x;
  int bid = blockIdx.x;
  int g = bid & 7, c = bid >> 3;
  if (t < 64) curl[t] = baseB[((size_t)g * 64 + c) * 64 + t];
  __syncthreads();
  int gN = g * NPER;
  const int4* src4 = (const int4*)(ei + (size_t)g * EPG + c * 4096);
  const int4* dst4 = (const int4*)(ei + EE + (size_t)g * EPG + c * 4096);
#pragma unroll
  for (int j = 0; j < 4; ++j) {
    int4 s4 = src4[j * 256 + t];
    int4 d4 = dst4[j * 256 + t];
    int dl, w, pos;
    dl = d4.x - gN; w = dl >> 9; pos = atomicAdd(&curl[w], 1); binned[pos] = s4.x | ((dl & 511) << 18);
    dl = d4.y - gN; w = dl >> 9; pos = atomicAdd(&curl[w], 1); binned[pos] = s4.y | ((dl & 511) << 18);
    dl = d4.z - gN; w = dl >> 9; pos = atomicAdd(&curl[w], 1); binned[pos] = s4.z | ((dl & 511) << 18);
    dl = d4.w - gN; w = dl >> 9; pos = atomicAdd(&curl[w], 1); binned[pos] = s4.w | ((dl & 511) << 18);
  }
}

// ---------------- binning pass 4: per-window CSR build fully in LDS (count, scan, fill)
// Produces exact offs/cnt/adj + dis/dx. Replaces k_count, k_scanA/B/C, k_fill2.
__global__ __launch_bounds__(512) void k_build(const int* __restrict__ binned, const int* __restrict__ winOff,
                                               const int* __restrict__ winCnt, const int* __restrict__ x,
                                               int* __restrict__ offs, int* __restrict__ cnt,
                                               float* __restrict__ dis, float2* __restrict__ dx,
                                               int* __restrict__ adj) {
  __shared__ int ebuf[EMAX];
  __shared__ int cntl[512];
  __shared__ int wsum[8];
  int t = threadIdx.x;
  int bid = blockIdx.x;
  int g = bid & 7, w = bid >> 3;
  int winIdx = g * 64 + w;
  int base = winOff[winIdx];
  int nE = winCnt[winIdx];
  if (nE > EMAX) nE = EMAX;   // statistically impossible; memory safety only
  for (int i = t; i < nE; i += 512) ebuf[i] = binned[base + i];
  cntl[t] = 0;
  __syncthreads();
  for (int i = t; i < nE; i += 512) atomicAdd(&cntl[ebuf[i] >> 18], 1);
  __syncthreads();
  int c = cntl[t];
  // block exclusive scan over 512 counts
  int lane = t & 63, wv = t >> 6;
  int incl = c;
#pragma unroll
  for (int o = 1; o < 64; o <<= 1) {
    int u = __shfl_up(incl, o);
    if (lane >= o) incl += u;
  }
  if (lane == 63) wsum[wv] = incl;
  __syncthreads();
  if (t == 0) {
    int r = 0;
#pragma unroll
    for (int i = 0; i < 8; ++i) { int v = wsum[i]; wsum[i] = r; r += v; }
  }
  __syncthreads();
  int ex = incl - c + wsum[wv];
  int node = g * NPER + w * 512 + t;
  offs[node] = base + ex;
  cnt[node] = c;
  float dn = rsqrtf((float)(c + 1));   // +1 self loop
  dis[node] = dn;
  dx[node] = make_float2(dn, __int_as_float(x[node]));
  cntl[t] = base + ex;                 // reuse as cursor
  __syncthreads();
  for (int i = t; i < nE; i += 512) {
    int v = ebuf[i];
    int pos = atomicAdd(&cntl[v >> 18], 1);
    adj[pos] = v & 0x3FFFF;
  }
}

// ---------------- M1 = emb_w @ W2  (8x64)
__global__ void k_m1(const float* __restrict__ emb, const float* __restrict__ W2, float* __restrict__ M1) {
  int t = threadIdx.x;  // 512 threads
  int c = t >> 6, j = t & 63;
  float acc = 0.f;
  for (int k = 0; k < 64; ++k) acc += emb[c * 64 + k] * W2[k * 64 + j];
  M1[c * 64 + j] = acc;
}

// ---------------- pack W3, W1 into f16 MFMA B-fragment layout.
// B-frag (16x16x32): lane l holds col=l&15, k=kk*32+(l>>4)*8+i  (i=0..7 contiguous)
__global__ __launch_bounds__(256) void k_pack(const float* __restrict__ W3, const float* __restrict__ W1,
                                              _Float16* __restrict__ W3p, _Float16* __restrict__ W1p) {
  int t = blockIdx.x * 256 + threadIdx.x;   // 5120 total
  if (t < 4096) {
    int jt = t >> 10, kk = (t >> 9) & 1, l = (t >> 3) & 63, i = t & 7;
    int k = kk * 32 + (l >> 4) * 8 + i;
    int j = jt * 16 + (l & 15);
    W3p[t] = (_Float16)W3[k * 64 + j];
  } else if (t < 5120) {
    int q = t - 4096;
    int kk = q >> 9, l = (q >> 3) & 63, i = q & 7;
    int k = kk * 32 + (l >> 4) * 8 + i;
    int c = l & 15;
    W1p[q] = (_Float16)W1[k * 16 + c];
  }
}

// ---------------- out1h = fp16( dis[n] * relu(W8row@M1 + b2) ); W8row gathered from CSR.
__global__ __launch_bounds__(256) void k_out1(const int* __restrict__ adj, const int* __restrict__ offs,
                                              const int* __restrict__ cnt, const float2* __restrict__ dx,
                                              const float* __restrict__ M1, const float* __restrict__ b2,
                                              __half2* __restrict__ out1h) {
  int tid = threadIdx.x;
  int bid = blockIdx.x;
  int swz = (bid & 7) * 2048 + (bid >> 3);    // XCD-local graph
  int node = swz * 16 + (tid >> 4);
  int t16 = tid & 15;
  float2 dxn = dx[node];
  float dn = dxn.x;
  int xc = __float_as_int(dxn.y);
  int off = offs[node], c = cnt[node];
  float wv[8] = {0.f, 0.f, 0.f, 0.f, 0.f, 0.f, 0.f, 0.f};
  for (int it = t16; it < c; it += 16) {
    int s = adj[off + it];
    float2 v = dx[s];
    int cls = __float_as_int(v.y);
#pragma unroll
    for (int k = 0; k < 8; ++k) wv[k] += (cls == k) ? v.x : 0.f;
  }
#pragma unroll
  for (int k = 0; k < 8; ++k) {
#pragma unroll
    for (int m = 1; m < 16; m <<= 1) wv[k] += __shfl_xor(wv[k], m);
    wv[k] = (wv[k] + ((k == xc) ? dn : 0.f)) * dn;   // + self (dis), scale by dis[d]
  }
  int j0 = t16 * 4;
  float o0 = b2[j0], o1 = b2[j0 + 1], o2 = b2[j0 + 2], o3 = b2[j0 + 3];
#pragma unroll
  for (int k = 0; k < 8; ++k) {
    f4 m = *(const f4*)&M1[k * 64 + j0];
    o0 += wv[k] * m.x; o1 += wv[k] * m.y; o2 += wv[k] * m.z; o3 += wv[k] * m.w;
  }
  __half2 h01 = __floats2half2_rn(fmaxf(o0, 0.f) * dn, fmaxf(o1, 0.f) * dn);
  __half2 h23 = __floats2half2_rn(fmaxf(o2, 0.f) * dn, fmaxf(o3, 0.f) * dn);
  size_t p = (size_t)node * 32 + t16 * 2;
  out1h[p] = h01;
  out1h[p + 1] = h23;
}

// ---------------- layer 2: CSR gather + MFMA(W3) + relu + MFMA(W1) + softmax -> d_out
__global__ __launch_bounds__(256) void k_layer2(const int* __restrict__ adj, const int* __restrict__ offs,
                                                const int* __restrict__ cnt, const float* __restrict__ dis,
                                                const __half2* __restrict__ out1h,
                                                const _Float16* __restrict__ W3p, const float* __restrict__ b3,
                                                const _Float16* __restrict__ W1p, const float* __restrict__ b1,
                                                float* __restrict__ dout) {
  __shared__ _Float16 aggh[16 * 64];   // [node][k] f16, XOR-swizzled rows (2 KB)
  __shared__ _Float16 o2h[16 * 64];    // [node][j] f16, XOR-swizzled rows (2 KB)
  int tid = threadIdx.x;
  int bid = blockIdx.x;
  int swz = (bid & 7) * 2048 + (bid >> 3);
  int lane = tid & 63;
  int w = tid >> 6;                    // wave id 0..3
  int sub = lane >> 4, part = lane & 15;
  int ndl = (w << 2) + sub;            // node-local 0..15
  int node = swz * 16 + ndl;

  // phase 1: agg = dn * sum(out1h[self] + out1h[neighbors])  (16 lanes x 4 cols per node)
  float dn = dis[node];
  int off = offs[node];
  int c = cnt[node];
  const __half2* sp = out1h + (size_t)node * 32 + part * 2;
  float2 f01 = __half22float2(sp[0]), f23 = __half22float2(sp[1]);
  float ax = f01.x, ay = f01.y, az = f23.x, aw = f23.y;   // self (prescaled)
  int it = 0;
  for (; it + 4 <= c; it += 4) {
    int s0 = adj[off + it], s1 = adj[off + it + 1], s2 = adj[off + it + 2], s3 = adj[off + it + 3];
    const __half2* p0 = out1h + (size_t)s0 * 32 + part * 2;
    const __half2* p1 = out1h + (size_t)s1 * 32 + part * 2;
    const __half2* p2 = out1h + (size_t)s2 * 32 + part * 2;
    const __half2* p3 = out1h + (size_t)s3 * 32 + part * 2;
    __half2 a0 = p0[0], c0 = p0[1], a1 = p1[0], c1 = p1[1];
    __half2 a2 = p2[0], c2 = p2[1], a3 = p3[0], c3 = p3[1];
    float2 u;
    u = __half22float2(a0); ax += u.x; ay += u.y;  u = __half22float2(c0); az += u.x; aw += u.y;
    u = __half22float2(a1); ax += u.x; ay += u.y;  u = __half22float2(c1); az += u.x; aw += u.y;
    u = __half22float2(a2); ax += u.x; ay += u.y;  u = __half22float2(c2); az += u.x; aw += u.y;
    u = __half22float2(a3); ax += u.x; ay += u.y;  u = __half22float2(c3); az += u.x; aw += u.y;
  }
  for (; it < c; ++it) {
    int s = adj[off + it];
    const __half2* hp = out1h + (size_t)s * 32 + part * 2;
    float2 g01 = __half22float2(hp[0]), g23 = __half22float2(hp[1]);
    ax += g01.x; ay += g01.y; az += g23.x; aw += g23.y;
  }
  // store agg row (f16) swizzled: byte = node*128 + part*8, ^= (node&7)<<4
  {
    half4 hv = { (_Float16)(dn * ax), (_Float16)(dn * ay), (_Float16)(dn * az), (_Float16)(dn * aw) };
    int byte = (ndl * 128 + part * 8) ^ ((ndl & 7) << 4);
    *(half4*)((char*)aggh + byte) = hv;
  }
  __syncthreads();

  // phase 3a: o2 = relu(agg @ W3 + b3), wave w owns W3 cols [16w,16w+16)
  f32x4 acc = {0.f, 0.f, 0.f, 0.f};
#pragma unroll
  for (int kk = 0; kk < 2; ++kk) {
    int row = lane & 15;
    int abyte = (row * 128 + kk * 64 + (lane >> 4) * 16) ^ ((row & 7) << 4);
    half8 afrag = *(const half8*)((const char*)aggh + abyte);
    half8 bfrag = *(const half8*)&W3p[((w * 2 + kk) * 64 + lane) * 8];
    acc = __builtin_amdgcn_mfma_f32_16x16x32_f16(afrag, bfrag, acc, 0, 0, 0);
  }
  {
    int colj = w * 16 + (lane & 15);
    float b3v = b3[colj];
#pragma unroll
    for (int r = 0; r < 4; ++r) {
      int nrow = (lane >> 4) * 4 + r;                    // node 0..15
      _Float16 hv = (_Float16)fmaxf(acc[r] + b3v, 0.f);
      int byte = (nrow * 128 + colj * 2) ^ ((nrow & 7) << 4);
      *(_Float16*)((char*)o2h + byte) = hv;
    }
  }
  __syncthreads();

  // phase 3b: s = o2 @ W1 + b1 (each wave computes full 16x16; wave w stores node%4==w rows)
  f32x4 acc2 = {0.f, 0.f, 0.f, 0.f};
#pragma unroll
  for (int kk = 0; kk < 2; ++kk) {
    int row = lane & 15;
    int abyte = (row * 128 + kk * 64 + (lane >> 4) * 16) ^ ((row & 7) << 4);
    half8 afrag = *(const half8*)((const char*)o2h + abyte);
    half8 bfrag = *(const half8*)&W1p[(kk * 64 + lane) * 8];
    acc2 = __builtin_amdgcn_mfma_f32_16x16x32_f16(afrag, bfrag, acc2, 0, 0, 0);
  }
  {
    float sv = acc2[w] + b1[lane & 15];                  // this wave's reg r=w: node=(lane>>4)*4+w
    float mx = sv;
#pragma unroll
    for (int m = 1; m < 16; m <<= 1) mx = fmaxf(mx, __shfl_xor(mx, m));
    float ex = expf(sv - mx);
    float sm = ex;
#pragma unroll
    for (int m = 1; m < 16; m <<= 1) sm += __shfl_xor(sm, m);
    int nrow = (lane >> 4) * 4 + w;
    dout[8 + (size_t)swz * 256 + nrow * 16 + (lane & 15)] = ex / sm;
  }
}

// ---------------- mincut num + den via CSR -> per-block partials (NO global atomics)
__global__ __launch_bounds__(256) void k_num(const int* __restrict__ adj, const int* __restrict__ offs,
                                             const int* __restrict__ cnt, const float* __restrict__ sb,
                                             float* __restrict__ numP, float* __restrict__ denP) {
  __shared__ float redn[16];
  __shared__ float redd[16];
  int tid = threadIdx.x;
  int bid = blockIdx.x;
  int swz = (bid & 7) * 2048 + (bid >> 3);
  int grp = tid >> 4, t16 = tid & 15;
  int node = swz * 16 + grp;
  int off = offs[node];
  int c = cnt[node];
  float sv = 0.f, sq = 0.f;
  int it = 0;
  for (; it + 4 <= c; it += 4) {
    int s0 = adj[off + it], s1 = adj[off + it + 1], s2 = adj[off + it + 2], s3 = adj[off + it + 3];
    float v0 = sb[(size_t)s0 * 16 + t16];
    float v1 = sb[(size_t)s1 * 16 + t16];
    float v2 = sb[(size_t)s2 * 16 + t16];
    float v3 = sb[(size_t)s3 * 16 + t16];
    sv += v0 + v1 + v2 + v3;
    sq += v0 * v0 + v1 * v1 + v2 * v2 + v3 * v3;
  }
  for (; it < c; ++it) {
    float v = sb[(size_t)adj[off + it] * 16 + t16];
    sv += v;
    sq += v * v;
  }
  float dot = sb[(size_t)node * 16 + t16] * sv;
#pragma unroll
  for (int m = 1; m < 16; m <<= 1) {
    dot += __shfl_xor(dot, m);
    sq  += __shfl_xor(sq, m);
  }
  if (t16 == 0) { redn[grp] = dot; redd[grp] = sq; }
  __syncthreads();
  if (tid == 0) {
    float a = 0.f, b = 0.f;
#pragma unroll
    for (int i = 0; i < 16; ++i) { a += redn[i]; b += redd[i]; }
    numP[swz] = a;
    denP[swz] = b;
  }
}

// ---------------- xp + SS per graph -> per-block partials (NO global atomics)
__global__ __launch_bounds__(256) void k_ssden(const float* __restrict__ sb,
                                               float* __restrict__ xpP, float* __restrict__ SSp) {
  __shared__ float sl[256 * 17];
  __shared__ float xpl[16];
  int t = threadIdx.x;
  int b = blockIdx.x;
  int t1 = t >> 4, t2 = t & 15;
  if (t < 16) xpl[t] = 0.f;
  int node = b * 256 + t;
  const f4* pr = (const f4*)&sb[(size_t)node * 16];
  f4 r0 = pr[0], r1 = pr[1], r2 = pr[2], r3 = pr[3];
  float* row = &sl[t * 17];
  row[0] = r0.x; row[1] = r0.y; row[2] = r0.z; row[3] = r0.w;
  row[4] = r1.x; row[5] = r1.y; row[6] = r1.z; row[7] = r1.w;
  row[8] = r2.x; row[9] = r2.y; row[10] = r2.z; row[11] = r2.w;
  row[12] = r3.x; row[13] = r3.y; row[14] = r3.z; row[15] = r3.w;
  __syncthreads();
  float ss = 0.f;
  for (int n = 0; n < 256; ++n) ss += sl[n * 17 + t1] * sl[n * 17 + t2];
  SSp[(size_t)b * 256 + t] = ss;
  float colsum = 0.f;
#pragma unroll
  for (int r = 0; r < 16; ++r) colsum += sl[(t1 * 16 + r) * 17 + t2];
  atomicAdd(&xpl[t2], colsum);           // LDS atomic (cheap)
  __syncthreads();
  if (t < 16) xpP[b * 16 + t] = xpl[t];
}

// ---------------- reduce partials into accum + per-graph o1 (8 blocks, one per graph)
// accum layout: [num 8][den 8][xp 128][o1g 8]  (152 floats)
__global__ __launch_bounds__(256) void k_red(const float* __restrict__ numP, const float* __restrict__ denP,
                                             const float* __restrict__ SSp, const float* __restrict__ xpP,
                                             float* __restrict__ accum) {
  __shared__ float r1[256], r2[256];
  __shared__ float bc;
  int g = blockIdx.x, t = threadIdx.x;
  // SS element t of graph g: sum 128 block-partials
  float acc = 0.f;
  for (int b = 0; b < 128; ++b) acc += SSp[((size_t)(g * 128 + b)) * 256 + t];
  // num/den: 2048 partials each
  float a = 0.f, d = 0.f;
  for (int i = 0; i < 8; ++i) {
    a += numP[g * 2048 + i * 256 + t];
    d += denP[g * 2048 + i * 256 + t];
  }
  r1[t] = a; r2[t] = d;
  __syncthreads();
  for (int off = 128; off > 0; off >>= 1) {
    if (t < off) { r1[t] += r1[t + off]; r2[t] += r2[t + off]; }
    __syncthreads();
  }
  if (t == 0) { accum[g] = r1[0]; accum[8 + g] = r2[0]; }
  // xp: 128 partials x 16
  if (t < 16) {
    float s = 0.f;
    for (int b = 0; b < 128; ++b) s += xpP[(g * 128 + b) * 16 + t];
    accum[16 + g * 16 + t] = s;
  }
  __syncthreads();
  // o1 for this graph: ||SS||_F, then ||SS/||SS|| - I/4||_F
  r1[t] = acc * acc;
  __syncthreads();
  for (int off = 128; off > 0; off >>= 1) {
    if (t < off) r1[t] += r1[t + off];
    __syncthreads();
  }
  if (t == 0) bc = sqrtf(r1[0]);
  __syncthreads();
  float dv = acc / bc - (((t >> 4) == (t & 15)) ? 0.25f : 0.f);
  r1[t] = dv * dv;
  __syncthreads();
  for (int off = 128; off > 0; off >>= 1) {
    if (t < off) r1[t] += r1[t + off];
    __syncthreads();
  }
  if (t == 0) accum[144 + g] = sqrtf(r1[0]);
}

// ---------------- scalars: mc1, o1, pred (tiny)
__global__ __launch_bounds__(64) void k_final(const float* __restrict__ accum, const float* __restrict__ ncells,
                                              const float* __restrict__ Wp, const float* __restrict__ bp,
                                              float* __restrict__ dout) {
  int t = threadIdx.x;
  const float* num = accum;
  const float* den = accum + 8;
  const float* xp  = accum + 16;
  const float* o1g = accum + 144;
  if (t == 0) {
    float m = 0.f, o = 0.f;
    for (int g = 0; g < 8; ++g) { m += -num[g] / den[g]; o += o1g[g]; }
    dout[8 + (size_t)NN * 16] = m / 8.f;
    dout[8 + (size_t)NN * 16 + 1] = o / 8.f;
  }
  if (t < 8) {
    float p = bp[0];
    for (int k = 0; k < 16; ++k) p += (xp[t * 16 + k] / ncells[t]) * Wp[k];
    dout[t] = p;
  }
}

extern "C" void kernel_launch(void* const* d_in, const int* in_sizes, int n_in,
                              void* d_out, int out_size, void* d_ws, size_t ws_size,
                              hipStream_t stream) {
  const int* x            = (const int*)d_in[0];
  const int* ei           = (const int*)d_in[1];   // int32 (JAX x64 disabled)
  const float* ncells     = (const float*)d_in[3];
  const float* emb        = (const float*)d_in[4];
  const float* W2         = (const float*)d_in[5];
  const float* b2         = (const float*)d_in[6];
  const float* W3         = (const float*)d_in[7];
  const float* b3         = (const float*)d_in[8];
  const float* W1         = (const float*)d_in[9];
  const float* b1         = (const float*)d_in[10];
  const float* Wp         = (const float*)d_in[11];
  const float* bp         = (const float*)d_in[12];
  float* dout = (float*)d_out;

  // workspace layout (~55 MB); every cell fully written before read each launch (no memset).
  char* w = (char*)d_ws;
  float* accum = (float*)w;                            // 152 used, pad 160
  float* dis   = accum + 160;                          // N
  float2* dx   = (float2*)(dis + NN);                  // N float2 (dis, x-bits)
  int* offs    = (int*)(dx + NN);                      // N
  int* cnt     = offs + NN;                            // N
  int* adj     = cnt + NN;                             // E
  float* M1    = (float*)(adj + EE);                   // 512
  _Float16* W3p = (_Float16*)(M1 + 512);               // 4096 halves
  _Float16* W1p = W3p + 4096;                          // 1024 halves
  __half2* out1h = (__half2*)(W1p + 1024);             // N*32 half2 = 32 MB
  float* numP  = (float*)(out1h + (size_t)NN * 32);    // 16384
  float* denP  = numP + 16384;                         // 16384
  float* SSp   = denP + 16384;                         // 1024*256
  float* xpP   = SSp + 1024 * 256;                     // 1024*16
  int* histT   = (int*)(xpP + 1024 * 16);              // 8*64*64
  int* baseB   = histT + 8 * 64 * 64;                  // 8*64*64
  int* winOff  = baseB + 8 * 64 * 64;                  // 512
  int* winCnt  = winOff + 512;                         // 512
  int* binned  = winCnt + 512;                         // E

  k_hist  <<<512, 256, 0, stream>>>(ei, histT);
  k_hscan <<<8, 64, 0, stream>>>(histT, winOff, winCnt, baseB);
  k_scat  <<<512, 256, 0, stream>>>(ei, baseB, binned);
  k_build <<<512, 512, 0, stream>>>(binned, winOff, winCnt, x, offs, cnt, dis, dx, adj);
  k_m1    <<<1, 512, 0, stream>>>(emb, W2, M1);
  k_pack  <<<20, 256, 0, stream>>>(W3, W1, W3p, W1p);
  k_out1  <<<16384, 256, 0, stream>>>(adj, offs, cnt, dx, M1, b2, out1h);
  k_layer2<<<16384, 256, 0, stream>>>(adj, offs, cnt, dis, out1h, W3p, b3, W1p, b1, dout);
  k_num   <<<16384, 256, 0, stream>>>(adj, offs, cnt, dout + 8, numP, denP);
  k_ssden <<<1024, 256, 0, stream>>>(dout + 8, xpP, SSp);
  k_red   <<<8, 256, 0, stream>>>(numP, denP, SSp, xpP, accum);
  k_final <<<1, 64, 0, stream>>>(accum, ncells, Wp, bp, dout);
}

// Round 9
// 269.242 us; speedup vs baseline: 3.2824x; 1.0026x over previous
//
#include <hip/hip_runtime.h>
#include <hip/hip_bf16.h>
#include <hip/hip_fp16.h>
#include <math.h>

#define NN 262144
#define EE 2097152
#define NPER 32768
#define EPG 262144   // edges per graph
#define EMAX 5120    // max edges per 512-node window (mean 4096, std 63; 16 sigma pad)

typedef float4 f4;
typedef __attribute__((ext_vector_type(4))) float f32x4;
typedef __attribute__((ext_vector_type(8))) _Float16 half8;

// ---------------- binning pass 1: histogram of dst-windows per (graph, 4096-edge chunk)
__global__ __launch_bounds__(256) void k_hist(const int* __restrict__ ei, int* __restrict__ histT) {
  __shared__ int histl[64];
  int t = threadIdx.x;
  int bid = blockIdx.x;
  int g = bid & 7, c = bid >> 3;
  if (t < 64) histl[t] = 0;
  __syncthreads();
  int gN = g * NPER;
  const int4* dst4 = (const int4*)(ei + EE + (size_t)g * EPG + c * 4096);
#pragma unroll
  for (int j = 0; j < 4; ++j) {
    int4 d4 = dst4[j * 256 + t];
    atomicAdd(&histl[(d4.x - gN) >> 9], 1);
    atomicAdd(&histl[(d4.y - gN) >> 9], 1);
    atomicAdd(&histl[(d4.z - gN) >> 9], 1);
    atomicAdd(&histl[(d4.w - gN) >> 9], 1);
  }
  __syncthreads();
  if (t < 64) histT[((size_t)g * 64 + t) * 64 + c] = histl[t];   // [g][w][c]
}

// ---------------- binning pass 2: per-window totals + exact scatter bases (1 wave per graph)
__global__ __launch_bounds__(64) void k_hscan(const int* __restrict__ histT, int* __restrict__ winOff,
                                              int* __restrict__ winCnt, int* __restrict__ baseB) {
  int g = blockIdx.x, w = threadIdx.x;   // 64 threads = 64 windows
  const int* hrow = histT + ((size_t)g * 64 + w) * 64;
  int tot = 0;
#pragma unroll
  for (int c = 0; c < 64; ++c) tot += hrow[c];
  int incl = tot;
#pragma unroll
  for (int o = 1; o < 64; o <<= 1) {
    int u = __shfl_up(incl, o);
    if (w >= o) incl += u;
  }
  int excl = incl - tot;
  int base = g * EPG + excl;
  winOff[g * 64 + w] = base;
  winCnt[g * 64 + w] = tot;
  int run = base;
  for (int c = 0; c < 64; ++c) {
    baseB[((size_t)g * 64 + c) * 64 + w] = run;
    run += hrow[c];
  }
}

// ---------------- binning pass 3: scatter edges into exact window bins (LDS cursors only)
__global__ __launch_bounds__(256) void k_scat(const int* __restrict__ ei, const int* __restrict__ baseB,
                                              int* __restrict__ binned) {
  __shared__ int curl[64];
  int t = threadIdx.x;
  int bid = blockIdx.x;
  int g = bid & 7, c = bid >> 3;
  if (t < 64) curl[t] = baseB[((size_t)g * 64 + c) * 64 + t];
  __syncthreads();
  int gN = g * NPER;
  const int4* src4 = (const int4*)(ei + (size_t)g * EPG + c * 4096);
  const int4* dst4 = (const int4*)(ei + EE + (size_t)g * EPG + c * 4096);
#pragma unroll
  for (int j = 0; j < 4; ++j) {
    int4 s4 = src4[j * 256 + t];
    int4 d4 = dst4[j * 256 + t];
    int dl, w, pos;
    dl = d4.x - gN; w = dl >> 9; pos = atomicAdd(&curl[w], 1); binned[pos] = s4.x | ((dl & 511) << 18);
    dl = d4.y - gN; w = dl >> 9; pos = atomicAdd(&curl[w], 1); binned[pos] = s4.y | ((dl & 511) << 18);
    dl = d4.z - gN; w = dl >> 9; pos = atomicAdd(&curl[w], 1); binned[pos] = s4.z | ((dl & 511) << 18);
    dl = d4.w - gN; w = dl >> 9; pos = atomicAdd(&curl[w], 1); binned[pos] = s4.w | ((dl & 511) << 18);
  }
}

// ---------------- binning pass 4: per-window CSR build fully in LDS (count, scan, fill)
__global__ __launch_bounds__(512) void k_build(const int* __restrict__ binned, const int* __restrict__ winOff,
                                               const int* __restrict__ winCnt, const int* __restrict__ x,
                                               int* __restrict__ offs, int* __restrict__ cnt,
                                               float2* __restrict__ dx, int* __restrict__ adj) {
  __shared__ int ebuf[EMAX];
  __shared__ int cntl[512];
  __shared__ int wsum[8];
  int t = threadIdx.x;
  int bid = blockIdx.x;
  int g = bid & 7, w = bid >> 3;
  int winIdx = g * 64 + w;
  int base = winOff[winIdx];
  int nE = winCnt[winIdx];
  if (nE > EMAX) nE = EMAX;   // statistically impossible; memory safety only
  for (int i = t; i < nE; i += 512) ebuf[i] = binned[base + i];
  cntl[t] = 0;
  __syncthreads();
  for (int i = t; i < nE; i += 512) atomicAdd(&cntl[ebuf[i] >> 18], 1);
  __syncthreads();
  int c = cntl[t];
  int lane = t & 63, wv = t >> 6;
  int incl = c;
#pragma unroll
  for (int o = 1; o < 64; o <<= 1) {
    int u = __shfl_up(incl, o);
    if (lane >= o) incl += u;
  }
  if (lane == 63) wsum[wv] = incl;
  __syncthreads();
  if (t == 0) {
    int r = 0;
#pragma unroll
    for (int i = 0; i < 8; ++i) { int v = wsum[i]; wsum[i] = r; r += v; }
  }
  __syncthreads();
  int ex = incl - c + wsum[wv];
  int node = g * NPER + w * 512 + t;
  offs[node] = base + ex;
  cnt[node] = c;
  float dn = rsqrtf((float)(c + 1));   // +1 self loop
  dx[node] = make_float2(dn, __int_as_float(x[node]));
  cntl[t] = base + ex;                 // reuse as cursor
  __syncthreads();
  for (int i = t; i < nE; i += 512) {
    int v = ebuf[i];
    int pos = atomicAdd(&cntl[v >> 18], 1);
    adj[pos] = v & 0x3FFFF;
  }
}

// ---------------- prep: M1 = emb_w@W2 + pack W3/W1 into f16 MFMA B-fragment layout (one launch)
// B-frag (16x16x32): lane l holds col=l&15, k=kk*32+(l>>4)*8+i  (i=0..7 contiguous)
__global__ __launch_bounds__(256) void k_prep(const float* __restrict__ emb, const float* __restrict__ W2,
                                              const float* __restrict__ W3, const float* __restrict__ W1,
                                              float* __restrict__ M1, _Float16* __restrict__ W3p,
                                              _Float16* __restrict__ W1p) {
  int bid = blockIdx.x;
  int t = bid * 256 + threadIdx.x;
  if (bid < 16) {                       // W3 pack, t in [0,4096)
    int jt = t >> 10, kk = (t >> 9) & 1, l = (t >> 3) & 63, i = t & 7;
    int k = kk * 32 + (l >> 4) * 8 + i;
    int j = jt * 16 + (l & 15);
    W3p[t] = (_Float16)W3[k * 64 + j];
  } else if (bid < 20) {                // W1 pack, q in [0,1024)
    int q = t - 4096;
    int kk = q >> 9, l = (q >> 3) & 63, i = q & 7;
    int k = kk * 32 + (l >> 4) * 8 + i;
    int c = l & 15;
    W1p[q] = (_Float16)W1[k * 16 + c];
  } else {                              // M1, idx in [0,512)
    int idx = t - 5120;
    int c = idx >> 6, j = idx & 63;
    float acc = 0.f;
    for (int k = 0; k < 64; ++k) acc += emb[c * 64 + k] * W2[k * 64 + j];
    M1[idx] = acc;
  }
}

// ---------------- w8 histogram + out1 per 512-node window (replaces old k_out1 CSR walk).
// Streams binned once (coalesced), LDS f32-atomic class accumulation, then each thread
// computes its node's full out1 row: out1h[n][j] = f16( dn * relu(b2[j] + sum_c wv[c]*M1[c][j]) ).
__global__ __launch_bounds__(512) void k_wout1(const int* __restrict__ binned, const int* __restrict__ winOff,
                                               const int* __restrict__ winCnt, const float2* __restrict__ dx,
                                               const float* __restrict__ M1, const float* __restrict__ b2,
                                               __half2* __restrict__ out1h) {
  __shared__ float w8l[512 * 8];   // 16 KB
  int t = threadIdx.x;
  int bid = blockIdx.x;
  int g = bid & 7, w = bid >> 3;
  int winIdx = g * 64 + w;
  int base = winOff[winIdx];
  int nE = winCnt[winIdx];
#pragma unroll
  for (int i = 0; i < 8; ++i) w8l[i * 512 + t] = 0.f;
  __syncthreads();
  for (int i = t; i < nE; i += 512) {
    int v = binned[base + i];
    int s = v & 0x3FFFF;
    int dl = v >> 18;
    float2 sv = dx[s];                 // (dis[s], x[s] bits) — L2-resident 256KB slice
    atomicAdd(&w8l[dl * 8 + __float_as_int(sv.y)], sv.x);
  }
  __syncthreads();
  int node = g * NPER + w * 512 + t;
  float2 dxn = dx[node];
  float dn = dxn.x;
  int xc = __float_as_int(dxn.y);
  float wv[8];
#pragma unroll
  for (int c = 0; c < 8; ++c) wv[c] = (w8l[t * 8 + c] + ((c == xc) ? dn : 0.f)) * dn;
  __half2 orow[32];
#pragma unroll
  for (int j2 = 0; j2 < 32; ++j2) {
    float oa = b2[j2 * 2], ob = b2[j2 * 2 + 1];
#pragma unroll
    for (int c = 0; c < 8; ++c) {      // M1/b2 wave-uniform -> scalar loads
      oa += wv[c] * M1[c * 64 + j2 * 2];
      ob += wv[c] * M1[c * 64 + j2 * 2 + 1];
    }
    orow[j2] = __floats2half2_rn(fmaxf(oa, 0.f) * dn, fmaxf(ob, 0.f) * dn);
  }
  f4* dstp = (f4*)(out1h + (size_t)node * 32);
  const f4* srcp = (const f4*)orow;
#pragma unroll
  for (int q = 0; q < 8; ++q) dstp[q] = srcp[q];
}

// ---------------- layer 2: CSR gather (8-deep, pk-f16 accum) + MFMA(W3) + relu + MFMA(W1) + softmax
__global__ __launch_bounds__(256) void k_layer2(const int* __restrict__ adj, const int* __restrict__ offs,
                                                const int* __restrict__ cnt, const float2* __restrict__ dx,
                                                const __half2* __restrict__ out1h,
                                                const _Float16* __restrict__ W3p, const float* __restrict__ b3,
                                                const _Float16* __restrict__ W1p, const float* __restrict__ b1,
                                                float* __restrict__ dout, __half* __restrict__ sbh) {
  __shared__ _Float16 aggh[16 * 64];   // [node][k] f16, XOR-swizzled rows (2 KB)
  __shared__ _Float16 o2h[16 * 64];    // [node][j] f16, XOR-swizzled rows (2 KB)
  int tid = threadIdx.x;
  int bid = blockIdx.x;
  int swz = (bid & 7) * 2048 + (bid >> 3);
  int lane = tid & 63;
  int w = tid >> 6;                    // wave id 0..3
  int sub = lane >> 4, part = lane & 15;
  int ndl = (w << 2) + sub;            // node-local 0..15
  int node = swz * 16 + ndl;

  // phase 1: agg = dn * sum(out1h[self] + out1h[neighbors]) — packed f16 accumulation
  float dn = dx[node].x;
  int off = offs[node];
  int c = cnt[node];
  const __half2* sp = out1h + ((size_t)node << 5) + (part << 1);
  __half2 a01 = sp[0], a23 = sp[1];    // self (prescaled by dis[src])
  int it = 0;
  for (; it + 8 <= c; it += 8) {
    int sA[8];
#pragma unroll
    for (int u = 0; u < 8; ++u) sA[u] = adj[off + it + u];
#pragma unroll
    for (int u = 0; u < 8; ++u) {
      const __half2* hp = out1h + (((size_t)sA[u]) << 5) + (part << 1);
      __half2 h0 = hp[0], h1 = hp[1];
      a01 = __hadd2(a01, h0);
      a23 = __hadd2(a23, h1);
    }
  }
  for (; it < c; ++it) {
    const __half2* hp = out1h + (((size_t)adj[off + it]) << 5) + (part << 1);
    __half2 h0 = hp[0], h1 = hp[1];
    a01 = __hadd2(a01, h0);
    a23 = __hadd2(a23, h1);
  }
  {
    __half2 dn2 = __float2half2_rn(dn);
    a01 = __hmul2(a01, dn2);
    a23 = __hmul2(a23, dn2);
    int byte = (ndl * 128 + part * 8) ^ ((ndl & 7) << 4);
    *(__half2*)((char*)aggh + byte) = a01;
    *(__half2*)((char*)aggh + byte + 4) = a23;
  }
  __syncthreads();

  // phase 3a: o2 = relu(agg @ W3 + b3), wave w owns W3 cols [16w,16w+16)
  f32x4 acc = {0.f, 0.f, 0.f, 0.f};
#pragma unroll
  for (int kk = 0; kk < 2; ++kk) {
    int row = lane & 15;
    int abyte = (row * 128 + kk * 64 + (lane >> 4) * 16) ^ ((row & 7) << 4);
    half8 afrag = *(const half8*)((const char*)aggh + abyte);
    half8 bfrag = *(const half8*)&W3p[((w * 2 + kk) * 64 + lane) * 8];
    acc = __builtin_amdgcn_mfma_f32_16x16x32_f16(afrag, bfrag, acc, 0, 0, 0);
  }
  {
    int colj = w * 16 + (lane & 15);
    float b3v = b3[colj];
#pragma unroll
    for (int r = 0; r < 4; ++r) {
      int nrow = (lane >> 4) * 4 + r;                    // node 0..15
      _Float16 hv = (_Float16)fmaxf(acc[r] + b3v, 0.f);
      int byte = (nrow * 128 + colj * 2) ^ ((nrow & 7) << 4);
      *(_Float16*)((char*)o2h + byte) = hv;
    }
  }
  __syncthreads();

  // phase 3b: s = o2 @ W1 + b1 (each wave computes full 16x16; wave w stores node%4==w rows)
  f32x4 acc2 = {0.f, 0.f, 0.f, 0.f};
#pragma unroll
  for (int kk = 0; kk < 2; ++kk) {
    int row = lane & 15;
    int abyte = (row * 128 + kk * 64 + (lane >> 4) * 16) ^ ((row & 7) << 4);
    half8 afrag = *(const half8*)((const char*)o2h + abyte);
    half8 bfrag = *(const half8*)&W1p[(kk * 64 + lane) * 8];
    acc2 = __builtin_amdgcn_mfma_f32_16x16x32_f16(afrag, bfrag, acc2, 0, 0, 0);
  }
  {
    float sv = acc2[w] + b1[lane & 15];                  // this wave's reg r=w: node=(lane>>4)*4+w
    float mx = sv;
#pragma unroll
    for (int m = 1; m < 16; m <<= 1) mx = fmaxf(mx, __shfl_xor(mx, m));
    float ex = expf(sv - mx);
    float sm = ex;
#pragma unroll
    for (int m = 1; m < 16; m <<= 1) sm += __shfl_xor(sm, m);
    float so = ex / sm;
    int nrow = (lane >> 4) * 4 + w;
    dout[8 + (size_t)swz * 256 + nrow * 16 + (lane & 15)] = so;
    sbh[((swz * 16 + nrow) << 4) + (lane & 15)] = __float2half(so);
  }
}

// ---------------- mincut num + den via CSR over fp16 s (8 lanes/node, 32 nodes/block)
__global__ __launch_bounds__(256) void k_num(const int* __restrict__ adj, const int* __restrict__ offs,
                                             const int* __restrict__ cnt, const __half2* __restrict__ sbh2,
                                             float* __restrict__ numP, float* __restrict__ denP) {
  __shared__ float redn[32];
  __shared__ float redd[32];
  int tid = threadIdx.x;
  int bid = blockIdx.x;                 // 8192 blocks
  int swz = (bid & 7) * 1024 + (bid >> 3);
  int grp = tid >> 3, t8 = tid & 7;
  int node = swz * 32 + grp;
  int off = offs[node];
  int c = cnt[node];
  float svx = 0.f, svy = 0.f, sq = 0.f;
  int it = 0;
  for (; it + 8 <= c; it += 8) {
    int sA[8];
#pragma unroll
    for (int u = 0; u < 8; ++u) sA[u] = adj[off + it + u];
#pragma unroll
    for (int u = 0; u < 8; ++u) {
      float2 v = __half22float2(sbh2[(sA[u] << 3) + t8]);
      svx += v.x; svy += v.y; sq += v.x * v.x + v.y * v.y;
    }
  }
  for (; it < c; ++it) {
    float2 v = __half22float2(sbh2[(adj[off + it] << 3) + t8]);
    svx += v.x; svy += v.y; sq += v.x * v.x + v.y * v.y;
  }
  float2 sf = __half22float2(sbh2[(node << 3) + t8]);
  float dot = sf.x * svx + sf.y * svy;
#pragma unroll
  for (int m = 1; m < 8; m <<= 1) {
    dot += __shfl_xor(dot, m);
    sq  += __shfl_xor(sq, m);
  }
  if (t8 == 0) { redn[grp] = dot; redd[grp] = sq; }
  __syncthreads();
  if (tid < 32) {
    float a = redn[tid], d = redd[tid];
#pragma unroll
    for (int m = 1; m < 32; m <<= 1) {
      a += __shfl_xor(a, m);
      d += __shfl_xor(d, m);
    }
    if (tid == 0) { numP[swz] = a; denP[swz] = d; }
  }
}

// ---------------- xp + SS per graph -> per-block partials (NO global atomics)
__global__ __launch_bounds__(256) void k_ssden(const float* __restrict__ sb,
                                               float* __restrict__ xpP, float* __restrict__ SSp) {
  __shared__ float sl[256 * 17];
  __shared__ float xpl[16];
  int t = threadIdx.x;
  int b = blockIdx.x;
  int t1 = t >> 4, t2 = t & 15;
  if (t < 16) xpl[t] = 0.f;
  int node = b * 256 + t;
  const f4* pr = (const f4*)&sb[(size_t)node * 16];
  f4 r0 = pr[0], r1 = pr[1], r2 = pr[2], r3 = pr[3];
  float* row = &sl[t * 17];
  row[0] = r0.x; row[1] = r0.y; row[2] = r0.z; row[3] = r0.w;
  row[4] = r1.x; row[5] = r1.y; row[6] = r1.z; row[7] = r1.w;
  row[8] = r2.x; row[9] = r2.y; row[10] = r2.z; row[11] = r2.w;
  row[12] = r3.x; row[13] = r3.y; row[14] = r3.z; row[15] = r3.w;
  __syncthreads();
  float ss = 0.f;
  for (int n = 0; n < 256; ++n) ss += sl[n * 17 + t1] * sl[n * 17 + t2];
  SSp[(size_t)b * 256 + t] = ss;
  float colsum = 0.f;
#pragma unroll
  for (int r = 0; r < 16; ++r) colsum += sl[(t1 * 16 + r) * 17 + t2];
  atomicAdd(&xpl[t2], colsum);           // LDS atomic (cheap)
  __syncthreads();
  if (t < 16) xpP[b * 16 + t] = xpl[t];
}

// ---------------- reduce partials into accum + per-graph o1 (8 blocks, one per graph)
// accum layout: [num 8][den 8][xp 128][o1g 8]  (152 floats)
__global__ __launch_bounds__(256) void k_red(const float* __restrict__ numP, const float* __restrict__ denP,
                                             const float* __restrict__ SSp, const float* __restrict__ xpP,
                                             float* __restrict__ accum) {
  __shared__ float r1[256], r2[256];
  __shared__ float bc;
  int g = blockIdx.x, t = threadIdx.x;
  float acc = 0.f;
  for (int b = 0; b < 128; ++b) acc += SSp[((size_t)(g * 128 + b)) * 256 + t];
  float a = 0.f, d = 0.f;
  for (int i = 0; i < 4; ++i) {
    a += numP[g * 1024 + i * 256 + t];
    d += denP[g * 1024 + i * 256 + t];
  }
  r1[t] = a; r2[t] = d;
  __syncthreads();
  for (int off = 128; off > 0; off >>= 1) {
    if (t < off) { r1[t] += r1[t + off]; r2[t] += r2[t + off]; }
    __syncthreads();
  }
  if (t == 0) { accum[g] = r1[0]; accum[8 + g] = r2[0]; }
  if (t < 16) {
    float s = 0.f;
    for (int b = 0; b < 128; ++b) s += xpP[(g * 128 + b) * 16 + t];
    accum[16 + g * 16 + t] = s;
  }
  __syncthreads();
  r1[t] = acc * acc;
  __syncthreads();
  for (int off = 128; off > 0; off >>= 1) {
    if (t < off) r1[t] += r1[t + off];
    __syncthreads();
  }
  if (t == 0) bc = sqrtf(r1[0]);
  __syncthreads();
  float dv = acc / bc - (((t >> 4) == (t & 15)) ? 0.25f : 0.f);
  r1[t] = dv * dv;
  __syncthreads();
  for (int off = 128; off > 0; off >>= 1) {
    if (t < off) r1[t] += r1[t + off];
    __syncthreads();
  }
  if (t == 0) accum[144 + g] = sqrtf(r1[0]);
}

// ---------------- scalars: mc1, o1, pred (tiny)
__global__ __launch_bounds__(64) void k_final(const float* __restrict__ accum, const float* __restrict__ ncells,
                                              const float* __restrict__ Wp, const float* __restrict__ bp,
                                              float* __restrict__ dout) {
  int t = threadIdx.x;
  const float* num = accum;
  const float* den = accum + 8;
  const float* xp  = accum + 16;
  const float* o1g = accum + 144;
  if (t == 0) {
    float m = 0.f, o = 0.f;
    for (int g = 0; g < 8; ++g) { m += -num[g] / den[g]; o += o1g[g]; }
    dout[8 + (size_t)NN * 16] = m / 8.f;
    dout[8 + (size_t)NN * 16 + 1] = o / 8.f;
  }
  if (t < 8) {
    float p = bp[0];
    for (int k = 0; k < 16; ++k) p += (xp[t * 16 + k] / ncells[t]) * Wp[k];
    dout[t] = p;
  }
}

extern "C" void kernel_launch(void* const* d_in, const int* in_sizes, int n_in,
                              void* d_out, int out_size, void* d_ws, size_t ws_size,
                              hipStream_t stream) {
  const int* x            = (const int*)d_in[0];
  const int* ei           = (const int*)d_in[1];   // int32 (JAX x64 disabled)
  const float* ncells     = (const float*)d_in[3];
  const float* emb        = (const float*)d_in[4];
  const float* W2         = (const float*)d_in[5];
  const float* b2         = (const float*)d_in[6];
  const float* W3         = (const float*)d_in[7];
  const float* b3         = (const float*)d_in[8];
  const float* W1         = (const float*)d_in[9];
  const float* b1         = (const float*)d_in[10];
  const float* Wp         = (const float*)d_in[11];
  const float* bp         = (const float*)d_in[12];
  float* dout = (float*)d_out;

  // workspace layout (~58 MB); every cell fully written before read each launch (no memset).
  char* w = (char*)d_ws;
  float* accum = (float*)w;                            // 152 used, pad 160
  float2* dx   = (float2*)(accum + 160);               // N float2 (dis, x-bits)
  int* offs    = (int*)(dx + NN);                      // N
  int* cnt     = offs + NN;                            // N
  int* adj     = cnt + NN;                             // E
  float* M1    = (float*)(adj + EE);                   // 512
  _Float16* W3p = (_Float16*)(M1 + 512);               // 4096 halves
  _Float16* W1p = W3p + 4096;                          // 1024 halves (pad to 1024)
  __half2* out1h = (__half2*)(W1p + 1024);             // N*32 half2 = 32 MB
  __half* sbh  = (__half*)(out1h + (size_t)NN * 32);   // N*16 half = 8 MB
  float* numP  = (float*)(sbh + (size_t)NN * 16);      // 8192
  float* denP  = numP + 8192;                          // 8192
  float* SSp   = denP + 8192;                          // 1024*256
  float* xpP   = SSp + 1024 * 256;                     // 1024*16
  int* histT   = (int*)(xpP + 1024 * 16);              // 8*64*64
  int* baseB   = histT + 8 * 64 * 64;                  // 8*64*64
  int* winOff  = baseB + 8 * 64 * 64;                  // 512
  int* winCnt  = winOff + 512;                         // 512
  int* binned  = winCnt + 512;                         // E

  k_hist  <<<512, 256, 0, stream>>>(ei, histT);
  k_hscan <<<8, 64, 0, stream>>>(histT, winOff, winCnt, baseB);
  k_scat  <<<512, 256, 0, stream>>>(ei, baseB, binned);
  k_build <<<512, 512, 0, stream>>>(binned, winOff, winCnt, x, offs, cnt, dx, adj);
  k_prep  <<<22, 256, 0, stream>>>(emb, W2, W3, W1, M1, W3p, W1p);
  k_wout1 <<<512, 512, 0, stream>>>(binned, winOff, winCnt, dx, M1, b2, out1h);
  k_layer2<<<16384, 256, 0, stream>>>(adj, offs, cnt, dx, out1h, W3p, b3, W1p, b1, dout, sbh);
  k_num   <<<8192, 256, 0, stream>>>(adj, offs, cnt, (const __half2*)sbh, numP, denP);
  k_ssden <<<1024, 256, 0, stream>>>(dout + 8, xpP, SSp);
  k_red   <<<8, 256, 0, stream>>>(numP, denP, SSp, xpP, accum);
  k_final <<<1, 64, 0, stream>>>(accum, ncells, Wp, bp, dout);
}